// Round 10
// baseline (172.623 us; speedup 1.0000x reference)
//
#include <hip/hip_runtime.h>
#include <hip/hip_bf16.h>
#include <math.h>

#define HD 128          // N_HEADS * OUT_FEATS
#define IN_F 256
#define NEG_SLOPE 0.2f
#define NMAX 50000      // problem-fixed node count (LDS histogram capacity)

typedef __attribute__((ext_vector_type(8))) short short8;
typedef __attribute__((ext_vector_type(4))) float f32x4;

__device__ __forceinline__ unsigned short f2bf(float x) {
    __hip_bfloat16 b = __float2bfloat16(x);
    return *(unsigned short*)&b;
}
__device__ __forceinline__ float bf2f(unsigned short u) {
    unsigned int v = ((unsigned int)u) << 16;
    float f;
    __builtin_memcpy(&f, &v, 4);
    return f;
}
__device__ __forceinline__ short8 pack8(float4 f0, float4 f1) {
    short8 v;
    v[0] = (short)f2bf(f0.x); v[1] = (short)f2bf(f0.y);
    v[2] = (short)f2bf(f0.z); v[3] = (short)f2bf(f0.w);
    v[4] = (short)f2bf(f1.x); v[5] = (short)f2bf(f1.y);
    v[6] = (short)f2bf(f1.z); v[7] = (short)f2bf(f1.w);
    return v;
}

// ---------------- weights f32 -> bf16 ----------------
__global__ void cvt_w_kernel(const float4* __restrict__ wfc, const float4* __restrict__ wres,
                             ushort4* __restrict__ w16, int n4each) {
    int idx = blockIdx.x * blockDim.x + threadIdx.x;
    if (idx >= 2 * n4each) return;
    float4 f = (idx < n4each) ? wfc[idx] : wres[idx - n4each];
    ushort4 u;
    u.x = f2bf(f.x); u.y = f2bf(f.y); u.z = f2bf(f.z); u.w = f2bf(f.w);
    w16[idx] = u;
}

// ---------------- per-chunk LDS histogram (uint16-packed, no global atomics) ----
__global__ __launch_bounds__(512) void hist_kernel(const int* __restrict__ src,
                                                   const int* __restrict__ dst,
                                                   unsigned short* __restrict__ pc_src,
                                                   unsigned short* __restrict__ pc_dst,
                                                   int N, int E, int chunk) {
    __shared__ unsigned int h[NMAX / 2];   // 100 KB packed uint16 counts
    int tid = threadIdx.x;
    int nh = N >> 1;                        // N even
    uint4* h4 = (uint4*)h;
    for (int i = tid; i < (nh >> 2); i += 512) h4[i] = make_uint4(0, 0, 0, 0);
    for (int i = (nh & ~3) + tid; i < nh; i += 512) h[i] = 0;
    __syncthreads();

    const int* arr = blockIdx.y ? src : dst;
    int e1 = min(E, (int)(blockIdx.x + 1) * chunk);
    for (int e = blockIdx.x * chunk + tid; e < e1; e += 512) {
        int v = arr[e];
        atomicAdd(&h[v >> 1], 1u << ((v & 1) << 4));
    }
    __syncthreads();

    unsigned short* pc = (blockIdx.y ? pc_src : pc_dst) + (size_t)blockIdx.x * N;
    uint4* pc4 = (uint4*)pc;
    for (int i = tid; i < (nh >> 2); i += 512) pc4[i] = h4[i];
    for (int i = (nh & ~3) + tid; i < nh; i += 512) ((unsigned int*)pc)[i] = h[i];
}

// ---------------- per-node chunk prefix (in place) + degrees + scan1 ----------------
__global__ __launch_bounds__(256) void sum_scan1_kernel(
    const unsigned short* __restrict__ pc_src, unsigned short* __restrict__ pc_dst,
    int* __restrict__ out_cnt, int* __restrict__ deg, int* __restrict__ bsum,
    int N, int C) {
    __shared__ int wsum[4];
    int n = blockIdx.x * 256 + threadIdx.x;
    int sd = 0;
    if (n < N) {
        int ss = 0;
        for (int c = 0; c < C; c++) {
            ss += pc_src[(size_t)c * N + n];
            unsigned short v = pc_dst[(size_t)c * N + n];
            pc_dst[(size_t)c * N + n] = (unsigned short)sd;  // exclusive chunk prefix
            sd += v;
        }
        out_cnt[n] = ss;
        deg[n] = sd;
    }
    int v = (n < N) ? sd : 0;
#pragma unroll
    for (int d = 1; d < 64; d <<= 1) v += __shfl_xor(v, d);
    if ((threadIdx.x & 63) == 0) wsum[threadIdx.x >> 6] = v;
    __syncthreads();
    if (threadIdx.x == 0) bsum[blockIdx.x] = wsum[0] + wsum[1] + wsum[2] + wsum[3];
}

// ---------------- scan of block sums ----------------
__global__ __launch_bounds__(256) void scan2_kernel(int* __restrict__ bsum, int nb,
                                                    int* __restrict__ row_start_N, int E) {
    __shared__ int wtot[4];
    int tid = threadIdx.x, lane = tid & 63, wid = tid >> 6;
    int v = (tid < nb) ? bsum[tid] : 0;
    int incl = v;
#pragma unroll
    for (int d = 1; d < 64; d <<= 1) {
        int t = __shfl_up(incl, d);
        if (lane >= d) incl += t;
    }
    if (lane == 63) wtot[wid] = incl;
    __syncthreads();
    int woff = 0;
    for (int w = 0; w < wid; w++) woff += wtot[w];
    if (tid < nb) bsum[tid] = woff + incl - v;  // exclusive block offset, in place
    if (tid == 0) *row_start_N = E;             // row_start[N]
}

__global__ __launch_bounds__(256) void scan3_kernel(const int* __restrict__ deg,
                                                    const int* __restrict__ boff,
                                                    int* __restrict__ row_start, int N) {
    __shared__ int wsum[4];
    int i = blockIdx.x * 256 + threadIdx.x;
    int lane = threadIdx.x & 63, wid = threadIdx.x >> 6;
    int v = (i < N) ? deg[i] : 0;
    int incl = v;
#pragma unroll
    for (int d = 1; d < 64; d <<= 1) {
        int t = __shfl_up(incl, d);
        if (lane >= d) incl += t;
    }
    if (lane == 63) wsum[wid] = incl;
    __syncthreads();
    int woff = 0;
    for (int w = 0; w < wid; w++) woff += wsum[w];
    int excl = boff[blockIdx.x] + woff + incl - v;
    if (i < N) row_start[i] = excl;
}

// ---------------- placement: LDS cursors seeded from chunk prefix ----------------
__global__ __launch_bounds__(512) void place_kernel(const int* __restrict__ src,
                                                    const int* __restrict__ dst,
                                                    const unsigned short* __restrict__ chunkpre,
                                                    const int* __restrict__ row_start,
                                                    int* __restrict__ esrc,
                                                    int N, int E, int chunk) {
    __shared__ unsigned int cur[NMAX / 2];   // packed uint16 cursors
    int tid = threadIdx.x;
    int nh = N >> 1;
    const unsigned short* cp = chunkpre + (size_t)blockIdx.x * N;
    const uint4* cp4 = (const uint4*)cp;
    uint4* cur4 = (uint4*)cur;
    for (int i = tid; i < (nh >> 2); i += 512) cur4[i] = cp4[i];
    for (int i = (nh & ~3) + tid; i < nh; i += 512) cur[i] = ((const unsigned int*)cp)[i];
    __syncthreads();

    int e1 = min(E, (int)(blockIdx.x + 1) * chunk);
    for (int e = blockIdx.x * chunk + tid; e < e1; e += 512) {
        int d = dst[e], s = src[e];
        int sh = (d & 1) << 4;
        unsigned int old = atomicAdd(&cur[d >> 1], 1u << sh);
        int rank = (old >> sh) & 0xffff;
        esrc[row_start[d] + rank] = s;
    }
}

// ---------------- fused GEMM: barrier-free, LDS-free ----------------
// Grid = row tiles of 32; 4 waves per block = 4 col panels of 64.
// B panel (64 cols x 256 K) preloaded to regs (AGPR-backed). Each lane loads
// its own A fragment directly from global f32 (2 x float4 per k-step), converts
// in-register, MFMAs. cols 0..127 -> h16 (normalized bf16) + el/er;
// cols 128..255 -> resid16 (bf16).
__global__ __launch_bounds__(256) void gemm_fused(
    const float* __restrict__ feat, const __hip_bfloat16* __restrict__ w16,
    const int* __restrict__ out_cnt, const float* __restrict__ attn_l,
    const float* __restrict__ attn_r, unsigned short* __restrict__ h16,
    float* __restrict__ el, float* __restrict__ er,
    unsigned short* __restrict__ resid16, int N) {
    int tid = threadIdx.x;
    int lane = tid & 63, wn = tid >> 6;
    int l15 = lane & 15, lg = lane >> 4;
    int colbase = wn * 64;
    int bm = blockIdx.x * 32;

    // ---- B panel preload: 4 col-frags x 8 k-steps, held in regs ----
    short8 breg[4][8];
#pragma unroll
    for (int ni = 0; ni < 4; ni++) {
        const __hip_bfloat16* bp = w16 + (size_t)(colbase + ni * 16 + l15) * IN_F + lg * 8;
#pragma unroll
        for (int kk = 0; kk < 8; kk++)
            breg[ni][kk] = *(const short8*)(bp + kk * 32);
    }

    // ---- per-lane A row pointers (clamped; garbage rows never stored) ----
    const float* arow[2];
#pragma unroll
    for (int mi = 0; mi < 2; mi++) {
        int r = bm + mi * 16 + l15;
        r = (r < N) ? r : (N - 1);
        arow[mi] = feat + (size_t)r * IN_F + lg * 8;
    }

    f32x4 acc[2][4];
#pragma unroll
    for (int i = 0; i < 2; i++)
#pragma unroll
        for (int j = 0; j < 4; j++) acc[i][j] = (f32x4){0.f, 0.f, 0.f, 0.f};

#pragma unroll
    for (int kk = 0; kk < 8; kk++) {
        short8 a[2];
#pragma unroll
        for (int mi = 0; mi < 2; mi++) {
            float4 f0 = *(const float4*)(arow[mi] + kk * 32);
            float4 f1 = *(const float4*)(arow[mi] + kk * 32 + 4);
            a[mi] = pack8(f0, f1);
        }
#pragma unroll
        for (int mi = 0; mi < 2; mi++)
#pragma unroll
            for (int ni = 0; ni < 4; ni++)
                acc[mi][ni] = __builtin_amdgcn_mfma_f32_16x16x32_bf16(
                    a[mi], breg[ni][kk], acc[mi][ni], 0, 0, 0);
    }

    // ---- epilogue. C/D layout: col = lane&15, row = 4*(lane>>4)+reg ----
    bool isH = (wn < 2);
    int colloc = colbase & 127;  // 0 or 64 within each half
    float alv[4], arv[4];
    if (isH) {
#pragma unroll
        for (int ni = 0; ni < 4; ni++) {
            int c = colbase + ni * 16 + l15;  // < 128; flat [H][32] == col index
            alv[ni] = attn_l[c];
            arv[ni] = attn_r[c];
        }
    }
#pragma unroll
    for (int mi = 0; mi < 2; mi++) {
#pragma unroll
        for (int reg = 0; reg < 4; reg++) {
            int r = bm + mi * 16 + lg * 4 + reg;
            bool valid = (r < N);
            int rr = valid ? r : 0;
            if (isH) {
                float nrm = rsqrtf(fmaxf((float)out_cnt[rr], 1.0f));
                float pl0 = 0.f, pl1 = 0.f, pr0 = 0.f, pr1 = 0.f;
#pragma unroll
                for (int ni = 0; ni < 4; ni++) {
                    float v = acc[mi][ni][reg];
                    if (valid)
                        h16[(size_t)r * HD + colloc + ni * 16 + l15] = f2bf(v * nrm);
                    if (ni < 2) { pl0 += v * alv[ni]; pr0 += v * arv[ni]; }
                    else        { pl1 += v * alv[ni]; pr1 += v * arv[ni]; }
                }
                pl0 *= nrm; pl1 *= nrm;  // el uses normalized h; er uses pre-norm h
#pragma unroll
                for (int m = 1; m < 16; m <<= 1) {
                    pl0 += __shfl_xor(pl0, m); pl1 += __shfl_xor(pl1, m);
                    pr0 += __shfl_xor(pr0, m); pr1 += __shfl_xor(pr1, m);
                }
                if (valid && (lane & 15) == 0) {
                    int hb = wn * 2;  // heads hb, hb+1
                    el[r * 4 + hb] = pl0;     el[r * 4 + hb + 1] = pl1;
                    er[r * 4 + hb] = pr0;     er[r * 4 + hb + 1] = pr1;
                }
            } else if (valid) {
#pragma unroll
                for (int ni = 0; ni < 4; ni++)
                    resid16[(size_t)r * HD + colloc + ni * 16 + l15] =
                        f2bf(acc[mi][ni][reg]);
            }
        }
    }
}

// ---------------- fused edge softmax + weighted scatter + final ----------------
// One wave per dst node, lane-transposed: 64 lanes = 4 edge-slots x 16 dim-lanes.
// 2-stage software pipeline: chunk i+1's esrc/el/h16 loads issued before
// computing chunk i. Final write = sc*acc + resid16 (out written exactly once).
__global__ __launch_bounds__(256) void agg_kernel(const unsigned short* __restrict__ h16,
                                                  const float* __restrict__ el,
                                                  const float* __restrict__ er,
                                                  const int* __restrict__ row_start,
                                                  const int* __restrict__ esrc,
                                                  const unsigned short* __restrict__ resid16,
                                                  float* __restrict__ out, int N) {
    int wid = threadIdx.x >> 6, lane = threadIdx.x & 63;
    int n = blockIdx.x * 4 + wid;
    if (n >= N) return;
    int es = lane >> 4;        // edge slot 0..3
    int l15 = lane & 15;
    int h = l15 >> 2;          // head owning this lane's 8 dims
    int d0 = l15 * 8;
    int beg = row_start[n], end = row_start[n + 1];
    float erh = er[n * 4 + h];
    float den = 0.f;
    float acc[8];
#pragma unroll
    for (int j = 0; j < 8; j++) acc[j] = 0.f;

    if (beg < end) {
        int s0, s1; bool ok0, ok1;
        float ev0, ev1; short8 hv0, hv1;
        // prologue: chunk 0
        {
            int i0 = beg + es, i1 = beg + 4 + es;
            ok0 = i0 < end; ok1 = i1 < end;
            s0 = esrc[ok0 ? i0 : beg];
            s1 = esrc[ok1 ? i1 : beg];
            ev0 = el[s0 * 4 + h]; ev1 = el[s1 * 4 + h];
            hv0 = *(const short8*)(h16 + (size_t)s0 * HD + d0);
            hv1 = *(const short8*)(h16 + (size_t)s1 * HD + d0);
        }
        for (int base = beg + 8; base < end; base += 8) {
            // issue next chunk's loads
            int i0 = base + es, i1 = base + 4 + es;
            bool p0 = i0 < end, p1 = i1 < end;
            int t0 = esrc[p0 ? i0 : beg];
            int t1 = esrc[p1 ? i1 : beg];
            float fv0 = el[t0 * 4 + h];
            float fv1 = el[t1 * 4 + h];
            short8 g0 = *(const short8*)(h16 + (size_t)t0 * HD + d0);
            short8 g1 = *(const short8*)(h16 + (size_t)t1 * HD + d0);
            // compute current chunk
            float e0 = ev0 + erh; e0 = (e0 > 0.f) ? e0 : NEG_SLOPE * e0;
            float e1 = ev1 + erh; e1 = (e1 > 0.f) ? e1 : NEG_SLOPE * e1;
            float ex0 = ok0 ? __expf(e0) : 0.f;
            float ex1 = ok1 ? __expf(e1) : 0.f;
            den += ex0 + ex1;
#pragma unroll
            for (int j = 0; j < 8; j++)
                acc[j] += ex0 * bf2f((unsigned short)hv0[j]) +
                          ex1 * bf2f((unsigned short)hv1[j]);
            // rotate
            ok0 = p0; ok1 = p1; ev0 = fv0; ev1 = fv1; hv0 = g0; hv1 = g1;
        }
        // epilogue: last chunk
        float e0 = ev0 + erh; e0 = (e0 > 0.f) ? e0 : NEG_SLOPE * e0;
        float e1 = ev1 + erh; e1 = (e1 > 0.f) ? e1 : NEG_SLOPE * e1;
        float ex0 = ok0 ? __expf(e0) : 0.f;
        float ex1 = ok1 ? __expf(e1) : 0.f;
        den += ex0 + ex1;
#pragma unroll
        for (int j = 0; j < 8; j++)
            acc[j] += ex0 * bf2f((unsigned short)hv0[j]) +
                      ex1 * bf2f((unsigned short)hv1[j]);
    }

    // reduce over the 4 edge slots (lanes differing in bits 4,5)
#pragma unroll
    for (int m = 16; m < 64; m <<= 1) {
        den += __shfl_xor(den, m);
#pragma unroll
        for (int j = 0; j < 8; j++) acc[j] += __shfl_xor(acc[j], m);
    }

    if (es == 0) {
        const unsigned short* rp = resid16 + (size_t)n * HD + d0;
        short8 rv = *(const short8*)rp;
        int indeg = end - beg;
        float sc = (indeg > 0) ? sqrtf((float)indeg) / den : 0.f;
        float o[8];
#pragma unroll
        for (int j = 0; j < 8; j++)
            o[j] = sc * acc[j] + bf2f((unsigned short)rv[j]);
        float* op = out + (size_t)n * HD + d0;
        *(float4*)op = make_float4(o[0], o[1], o[2], o[3]);
        *(float4*)(op + 4) = make_float4(o[4], o[5], o[6], o[7]);
    }
}

extern "C" void kernel_launch(void* const* d_in, const int* in_sizes, int n_in,
                              void* d_out, int out_size, void* d_ws, size_t ws_size,
                              hipStream_t stream) {
    const float* feat   = (const float*)d_in[0];
    const int*   src    = (const int*)d_in[1];
    const int*   dst    = (const int*)d_in[2];
    const float* W_fc   = (const float*)d_in[3];
    const float* attn_l = (const float*)d_in[4];
    const float* attn_r = (const float*)d_in[5];
    const float* W_res  = (const float*)d_in[6];
    float* out = (float*)d_out;

    int N = in_sizes[0] / IN_F;   // 50000
    int E = in_sizes[1];          // 800000
    int nb = (N + 255) / 256;     // 196 (<= 256 for scan2)

    size_t off = 0;
    auto alloc = [&](size_t bytes) {
        size_t o = off;
        off = (off + bytes + 255) & ~(size_t)255;
        return o;
    };
    char* ws = (char*)d_ws;
    unsigned short* h16     = (unsigned short*)(ws + alloc((size_t)N * HD * 2));
    unsigned short* resid16 = (unsigned short*)(ws + alloc((size_t)N * HD * 2));
    __hip_bfloat16* w16     = (__hip_bfloat16*)(ws + alloc((size_t)2 * HD * IN_F * 2));
    float* el               = (float*)(ws + alloc((size_t)N * 4 * 4));
    float* er               = (float*)(ws + alloc((size_t)N * 4 * 4));
    int* out_cnt            = (int*)(ws + alloc((size_t)N * 4));
    int* deg                = (int*)(ws + alloc((size_t)N * 4));
    int* row_start          = (int*)(ws + alloc((size_t)(N + 1) * 4));
    int* bsum               = (int*)(ws + alloc((size_t)nb * 4));
    int* esrc               = (int*)(ws + alloc((size_t)E * 4));

    // runtime-adaptive chunk count: each chunk needs 2 uint16 rows of N
    size_t per_chunk = (size_t)4 * N;
    size_t avail = (ws_size > off + 4096) ? (ws_size - off - 4096) : 0;
    int C = (int)(avail / per_chunk);
    if (C > 128) C = 128;
    if (C < 32) C = 32;           // round-6 footprint proved safe
    unsigned short* pc_dst = (unsigned short*)(ws + alloc((size_t)C * N * 2));
    unsigned short* pc_src = (unsigned short*)(ws + alloc((size_t)C * N * 2));
    int chunk = (E + C - 1) / C;

    int n4each = HD * IN_F / 4;
    cvt_w_kernel<<<(2 * n4each + 255) / 256, 256, 0, stream>>>(
        (const float4*)W_fc, (const float4*)W_res, (ushort4*)w16, n4each);

    hist_kernel<<<dim3(C, 2), 512, 0, stream>>>(src, dst, pc_src, pc_dst, N, E, chunk);
    sum_scan1_kernel<<<nb, 256, 0, stream>>>(pc_src, pc_dst, out_cnt, deg, bsum, N, C);
    scan2_kernel<<<1, 256, 0, stream>>>(bsum, nb, row_start + N, E);
    scan3_kernel<<<nb, 256, 0, stream>>>(deg, bsum, row_start, N);
    place_kernel<<<C, 512, 0, stream>>>(src, dst, pc_dst, row_start, esrc, N, E, chunk);

    gemm_fused<<<(N + 31) / 32, 256, 0, stream>>>(feat, (const __hip_bfloat16*)w16,
                                                  out_cnt, attn_l, attn_r,
                                                  h16, el, er, resid16, N);

    int nb4 = (N + 3) / 4;
    agg_kernel<<<nb4, 256, 0, stream>>>(h16, el, er, row_start, esrc, resid16, out, N);
}

// Round 11
// 158.622 us; speedup vs baseline: 1.0883x; 1.0883x over previous
//
#include <hip/hip_runtime.h>
#include <hip/hip_bf16.h>
#include <math.h>

#define HD 128          // N_HEADS * OUT_FEATS
#define IN_F 256
#define NEG_SLOPE 0.2f
#define NMAX 50000      // problem-fixed node count (LDS histogram capacity)

typedef __attribute__((ext_vector_type(8))) short short8;
typedef __attribute__((ext_vector_type(4))) float f32x4;

__device__ __forceinline__ unsigned short f2bf(float x) {
    __hip_bfloat16 b = __float2bfloat16(x);
    return *(unsigned short*)&b;
}
__device__ __forceinline__ float bf2f(unsigned short u) {
    unsigned int v = ((unsigned int)u) << 16;
    float f;
    __builtin_memcpy(&f, &v, 4);
    return f;
}
__device__ __forceinline__ short8 pack8(float4 f0, float4 f1) {
    short8 v;
    v[0] = (short)f2bf(f0.x); v[1] = (short)f2bf(f0.y);
    v[2] = (short)f2bf(f0.z); v[3] = (short)f2bf(f0.w);
    v[4] = (short)f2bf(f1.x); v[5] = (short)f2bf(f1.y);
    v[6] = (short)f2bf(f1.z); v[7] = (short)f2bf(f1.w);
    return v;
}

// ---------------- weights f32 -> bf16 ----------------
__global__ void cvt_w_kernel(const float4* __restrict__ wfc, const float4* __restrict__ wres,
                             ushort4* __restrict__ w16, int n4each) {
    int idx = blockIdx.x * blockDim.x + threadIdx.x;
    if (idx >= 2 * n4each) return;
    float4 f = (idx < n4each) ? wfc[idx] : wres[idx - n4each];
    ushort4 u;
    u.x = f2bf(f.x); u.y = f2bf(f.y); u.z = f2bf(f.z); u.w = f2bf(f.w);
    w16[idx] = u;
}

// ---------------- attention-projection columns: ew16[16][256] ----------------
// rows 0-3: al_w[h][k] = sum_d attn_l[h,d] * W_fc[h*32+d][k]; rows 4-7: ar_w; 8-15: 0.
__global__ __launch_bounds__(256) void ew_kernel(const float* __restrict__ wfc,
                                                 const float* __restrict__ attn_l,
                                                 const float* __restrict__ attn_r,
                                                 unsigned short* __restrict__ ew16) {
    int h = blockIdx.x;          // 4 blocks
    int k = threadIdx.x;         // 256
    float sl = 0.f, sr = 0.f;
#pragma unroll 8
    for (int d = 0; d < 32; d++) {
        float w = wfc[(size_t)(h * 32 + d) * IN_F + k];
        sl += attn_l[h * 32 + d] * w;
        sr += attn_r[h * 32 + d] * w;
    }
    ew16[h * IN_F + k] = f2bf(sl);
    ew16[(4 + h) * IN_F + k] = f2bf(sr);
    ew16[(8 + h) * IN_F + k] = 0;
    ew16[(12 + h) * IN_F + k] = 0;
}

// ---------------- per-chunk LDS histogram (uint16-packed, no global atomics) ----
__global__ __launch_bounds__(512) void hist_kernel(const int* __restrict__ src,
                                                   const int* __restrict__ dst,
                                                   unsigned short* __restrict__ pc_src,
                                                   unsigned short* __restrict__ pc_dst,
                                                   int N, int E, int chunk) {
    __shared__ unsigned int h[NMAX / 2];   // 100 KB packed uint16 counts
    int tid = threadIdx.x;
    int nh = N >> 1;                        // N even
    uint4* h4 = (uint4*)h;
    for (int i = tid; i < (nh >> 2); i += 512) h4[i] = make_uint4(0, 0, 0, 0);
    for (int i = (nh & ~3) + tid; i < nh; i += 512) h[i] = 0;
    __syncthreads();

    const int* arr = blockIdx.y ? src : dst;
    int e1 = min(E, (int)(blockIdx.x + 1) * chunk);
    for (int e = blockIdx.x * chunk + tid; e < e1; e += 512) {
        int v = arr[e];
        atomicAdd(&h[v >> 1], 1u << ((v & 1) << 4));
    }
    __syncthreads();

    unsigned short* pc = (blockIdx.y ? pc_src : pc_dst) + (size_t)blockIdx.x * N;
    uint4* pc4 = (uint4*)pc;
    for (int i = tid; i < (nh >> 2); i += 512) pc4[i] = h4[i];
    for (int i = (nh & ~3) + tid; i < nh; i += 512) ((unsigned int*)pc)[i] = h[i];
}

// ---------------- per-node chunk prefix (in place) + degrees + scan1 ----------------
__global__ __launch_bounds__(256) void sum_scan1_kernel(
    const unsigned short* __restrict__ pc_src, unsigned short* __restrict__ pc_dst,
    int* __restrict__ out_cnt, int* __restrict__ deg, int* __restrict__ bsum,
    int N, int C) {
    __shared__ int wsum[4];
    int n = blockIdx.x * 256 + threadIdx.x;
    int sd = 0;
    if (n < N) {
        int ss = 0;
        for (int c = 0; c < C; c++) {
            ss += pc_src[(size_t)c * N + n];
            unsigned short v = pc_dst[(size_t)c * N + n];
            pc_dst[(size_t)c * N + n] = (unsigned short)sd;  // exclusive chunk prefix
            sd += v;
        }
        out_cnt[n] = ss;
        deg[n] = sd;
    }
    int v = (n < N) ? sd : 0;
#pragma unroll
    for (int d = 1; d < 64; d <<= 1) v += __shfl_xor(v, d);
    if ((threadIdx.x & 63) == 0) wsum[threadIdx.x >> 6] = v;
    __syncthreads();
    if (threadIdx.x == 0) bsum[blockIdx.x] = wsum[0] + wsum[1] + wsum[2] + wsum[3];
}

// ---------------- scan of block sums ----------------
__global__ __launch_bounds__(256) void scan2_kernel(int* __restrict__ bsum, int nb,
                                                    int* __restrict__ row_start_N, int E) {
    __shared__ int wtot[4];
    int tid = threadIdx.x, lane = tid & 63, wid = tid >> 6;
    int v = (tid < nb) ? bsum[tid] : 0;
    int incl = v;
#pragma unroll
    for (int d = 1; d < 64; d <<= 1) {
        int t = __shfl_up(incl, d);
        if (lane >= d) incl += t;
    }
    if (lane == 63) wtot[wid] = incl;
    __syncthreads();
    int woff = 0;
    for (int w = 0; w < wid; w++) woff += wtot[w];
    if (tid < nb) bsum[tid] = woff + incl - v;  // exclusive block offset, in place
    if (tid == 0) *row_start_N = E;             // row_start[N]
}

__global__ __launch_bounds__(256) void scan3_kernel(const int* __restrict__ deg,
                                                    const int* __restrict__ boff,
                                                    int* __restrict__ row_start, int N) {
    __shared__ int wsum[4];
    int i = blockIdx.x * 256 + threadIdx.x;
    int lane = threadIdx.x & 63, wid = threadIdx.x >> 6;
    int v = (i < N) ? deg[i] : 0;
    int incl = v;
#pragma unroll
    for (int d = 1; d < 64; d <<= 1) {
        int t = __shfl_up(incl, d);
        if (lane >= d) incl += t;
    }
    if (lane == 63) wsum[wid] = incl;
    __syncthreads();
    int woff = 0;
    for (int w = 0; w < wid; w++) woff += wsum[w];
    int excl = boff[blockIdx.x] + woff + incl - v;
    if (i < N) row_start[i] = excl;
}

// ---------------- placement: LDS cursors seeded from chunk prefix ----------------
__global__ __launch_bounds__(512) void place_kernel(const int* __restrict__ src,
                                                    const int* __restrict__ dst,
                                                    const unsigned short* __restrict__ chunkpre,
                                                    const int* __restrict__ row_start,
                                                    int* __restrict__ esrc,
                                                    int N, int E, int chunk) {
    __shared__ unsigned int cur[NMAX / 2];   // packed uint16 cursors
    int tid = threadIdx.x;
    int nh = N >> 1;
    const unsigned short* cp = chunkpre + (size_t)blockIdx.x * N;
    const uint4* cp4 = (const uint4*)cp;
    uint4* cur4 = (uint4*)cur;
    for (int i = tid; i < (nh >> 2); i += 512) cur4[i] = cp4[i];
    for (int i = (nh & ~3) + tid; i < nh; i += 512) cur[i] = ((const unsigned int*)cp)[i];
    __syncthreads();

    int e1 = min(E, (int)(blockIdx.x + 1) * chunk);
    for (int e = blockIdx.x * chunk + tid; e < e1; e += 512) {
        int d = dst[e], s = src[e];
        int sh = (d & 1) << 4;
        unsigned int old = atomicAdd(&cur[d >> 1], 1u << sh);
        int rank = (old >> sh) & 0xffff;
        esrc[row_start[d] + rank] = s;
    }
}

// ---------------- fused GEMM: el/er as columns, LDS-transposed coalesced output ----
// Grid = row tiles of 32; 4 waves = 4 col panels of 64. Wave 0 additionally
// computes el/er via the ew16 B-fragment. Output staged through LDS so all
// global stores are coalesced dwordx4. No scattered sub-dword global stores.
__global__ __launch_bounds__(256, 4) void gemm_fused(
    const float* __restrict__ feat, const __hip_bfloat16* __restrict__ w16,
    const __hip_bfloat16* __restrict__ ew16, const int* __restrict__ out_cnt,
    unsigned short* __restrict__ h16, unsigned short* __restrict__ resid16,
    float* __restrict__ el, float* __restrict__ er, int N) {
    __shared__ unsigned short sA[32 * 256];  // 16 KiB: input stage, then output stage
    int tid = threadIdx.x;
    int lane = tid & 63, wn = tid >> 6;
    int l15 = lane & 15, lg = lane >> 4;
    int colbase = wn * 64;
    int bm = blockIdx.x * 32;

    // ---- stage A: f32 -> bf16 into LDS (32 rows x 32 granules, XOR swizzled) ----
#pragma unroll
    for (int i = 0; i < 4; i++) {
        int G = i * 256 + tid;
        int row = G >> 5, gc = G & 31;
        int gm = bm + row;
        gm = (gm < N) ? gm : (N - 1);
        const float4* fp = (const float4*)(feat + (size_t)gm * IN_F + gc * 8);
        float4 f0 = fp[0], f1 = fp[1];
        *(short8*)&sA[row * 256 + ((gc ^ (row & 7)) * 8)] = pack8(f0, f1);
    }
    __syncthreads();

    const __hip_bfloat16* bp[4];
#pragma unroll
    for (int ni = 0; ni < 4; ni++)
        bp[ni] = w16 + (size_t)(colbase + ni * 16 + l15) * IN_F + lg * 8;
    const __hip_bfloat16* ep = ew16 + (size_t)l15 * IN_F + lg * 8;
    bool w0 = (wn == 0);

    f32x4 acc[2][4], accE[2];
#pragma unroll
    for (int i = 0; i < 2; i++) {
        accE[i] = (f32x4){0.f, 0.f, 0.f, 0.f};
#pragma unroll
        for (int j = 0; j < 4; j++) acc[i][j] = (f32x4){0.f, 0.f, 0.f, 0.f};
    }

#pragma unroll
    for (int kk = 0; kk < 8; kk++) {
        short8 a[2], b[4];
#pragma unroll
        for (int mi = 0; mi < 2; mi++) {
            int row = mi * 16 + l15;
            int gs = (kk * 4 + lg) ^ (row & 7);
            a[mi] = *(const short8*)&sA[row * 256 + gs * 8];
        }
#pragma unroll
        for (int ni = 0; ni < 4; ni++) b[ni] = *(const short8*)(bp[ni] + kk * 32);
#pragma unroll
        for (int mi = 0; mi < 2; mi++)
#pragma unroll
            for (int ni = 0; ni < 4; ni++)
                acc[mi][ni] = __builtin_amdgcn_mfma_f32_16x16x32_bf16(
                    a[mi], b[ni], acc[mi][ni], 0, 0, 0);
        if (w0) {
            short8 be = *(const short8*)(ep + kk * 32);
#pragma unroll
            for (int mi = 0; mi < 2; mi++)
                accE[mi] = __builtin_amdgcn_mfma_f32_16x16x32_bf16(
                    a[mi], be, accE[mi], 0, 0, 0);
        }
    }
    __syncthreads();   // all reads of sA complete; safe to reuse as output stage

    // ---- write acc to LDS (bf16, XOR-swizzled by row), el/er direct to global ----
    bool isH = (wn < 2);
#pragma unroll
    for (int mi = 0; mi < 2; mi++) {
#pragma unroll
        for (int reg = 0; reg < 4; reg++) {
            int rl = mi * 16 + lg * 4 + reg;   // local row 0..31
            int r = bm + rl;
            float nrm = 1.0f;
            if (isH) {
                int rr = (r < N) ? r : 0;
                nrm = rsqrtf(fmaxf((float)out_cnt[rr], 1.0f));
            }
#pragma unroll
            for (int ni = 0; ni < 4; ni++) {
                int col = colbase + ni * 16 + l15;
                float v = acc[mi][ni][reg] * nrm;   // nrm==1 for resid waves
                sA[rl * 256 + (col ^ ((rl & 7) << 4))] = f2bf(v);
            }
            if (w0 && r < N) {
                float ev = accE[mi][reg];   // C/D: col = lane&15 -> l15<4 el, 4..7 er
                if (l15 < 4) el[r * 4 + l15] = ev * nrm;
                else if (l15 < 8) er[r * 4 + (l15 - 4)] = ev;
            }
        }
    }
    __syncthreads();

    // ---- coalesced writeback: thread t -> row t>>3, 16-col segment t&7 ----
    int hrow = tid >> 3, seg = tid & 7;
    int gr = bm + hrow;
    if (gr < N) {
        int base = hrow * 256;
        int ss = ((seg ^ (hrow & 7)) << 4);   // swizzled segment start (16 cols)
        short8 hv0 = *(const short8*)&sA[base + ss];
        short8 hv1 = *(const short8*)&sA[base + ss + 8];
        short8 rv0 = *(const short8*)&sA[base + 128 + ss];
        short8 rv1 = *(const short8*)&sA[base + 128 + ss + 8];
        unsigned short* hp = h16 + (size_t)gr * HD + seg * 16;
        unsigned short* rp = resid16 + (size_t)gr * HD + seg * 16;
        *(short8*)hp = hv0;
        *(short8*)(hp + 8) = hv1;
        *(short8*)rp = rv0;
        *(short8*)(rp + 8) = rv1;
    }
}

// ---------------- fused edge softmax + weighted scatter + final ----------------
// One wave per dst node, lane-transposed: 64 lanes = 4 edge-slots x 16 dim-lanes.
// 2-stage software pipeline; final write = sc*acc + resid16 (out written once).
__global__ __launch_bounds__(256) void agg_kernel(const unsigned short* __restrict__ h16,
                                                  const float* __restrict__ el,
                                                  const float* __restrict__ er,
                                                  const int* __restrict__ row_start,
                                                  const int* __restrict__ esrc,
                                                  const unsigned short* __restrict__ resid16,
                                                  float* __restrict__ out, int N) {
    int wid = threadIdx.x >> 6, lane = threadIdx.x & 63;
    int n = blockIdx.x * 4 + wid;
    if (n >= N) return;
    int es = lane >> 4;        // edge slot 0..3
    int l15 = lane & 15;
    int h = l15 >> 2;          // head owning this lane's 8 dims
    int d0 = l15 * 8;
    int beg = row_start[n], end = row_start[n + 1];
    float erh = er[n * 4 + h];
    float den = 0.f;
    float acc[8];
#pragma unroll
    for (int j = 0; j < 8; j++) acc[j] = 0.f;

    if (beg < end) {
        bool ok0, ok1;
        float ev0, ev1; short8 hv0, hv1;
        {
            int i0 = beg + es, i1 = beg + 4 + es;
            ok0 = i0 < end; ok1 = i1 < end;
            int s0 = esrc[ok0 ? i0 : beg];
            int s1 = esrc[ok1 ? i1 : beg];
            ev0 = el[s0 * 4 + h]; ev1 = el[s1 * 4 + h];
            hv0 = *(const short8*)(h16 + (size_t)s0 * HD + d0);
            hv1 = *(const short8*)(h16 + (size_t)s1 * HD + d0);
        }
        for (int base = beg + 8; base < end; base += 8) {
            int i0 = base + es, i1 = base + 4 + es;
            bool p0 = i0 < end, p1 = i1 < end;
            int t0 = esrc[p0 ? i0 : beg];
            int t1 = esrc[p1 ? i1 : beg];
            float fv0 = el[t0 * 4 + h];
            float fv1 = el[t1 * 4 + h];
            short8 g0 = *(const short8*)(h16 + (size_t)t0 * HD + d0);
            short8 g1 = *(const short8*)(h16 + (size_t)t1 * HD + d0);
            float e0 = ev0 + erh; e0 = (e0 > 0.f) ? e0 : NEG_SLOPE * e0;
            float e1 = ev1 + erh; e1 = (e1 > 0.f) ? e1 : NEG_SLOPE * e1;
            float ex0 = ok0 ? __expf(e0) : 0.f;
            float ex1 = ok1 ? __expf(e1) : 0.f;
            den += ex0 + ex1;
#pragma unroll
            for (int j = 0; j < 8; j++)
                acc[j] += ex0 * bf2f((unsigned short)hv0[j]) +
                          ex1 * bf2f((unsigned short)hv1[j]);
            ok0 = p0; ok1 = p1; ev0 = fv0; ev1 = fv1; hv0 = g0; hv1 = g1;
        }
        float e0 = ev0 + erh; e0 = (e0 > 0.f) ? e0 : NEG_SLOPE * e0;
        float e1 = ev1 + erh; e1 = (e1 > 0.f) ? e1 : NEG_SLOPE * e1;
        float ex0 = ok0 ? __expf(e0) : 0.f;
        float ex1 = ok1 ? __expf(e1) : 0.f;
        den += ex0 + ex1;
#pragma unroll
        for (int j = 0; j < 8; j++)
            acc[j] += ex0 * bf2f((unsigned short)hv0[j]) +
                      ex1 * bf2f((unsigned short)hv1[j]);
    }

#pragma unroll
    for (int m = 16; m < 64; m <<= 1) {
        den += __shfl_xor(den, m);
#pragma unroll
        for (int j = 0; j < 8; j++) acc[j] += __shfl_xor(acc[j], m);
    }

    if (es == 0) {
        const unsigned short* rp = resid16 + (size_t)n * HD + d0;
        short8 rv = *(const short8*)rp;
        int indeg = end - beg;
        float sc = (indeg > 0) ? sqrtf((float)indeg) / den : 0.f;
        float o[8];
#pragma unroll
        for (int j = 0; j < 8; j++)
            o[j] = sc * acc[j] + bf2f((unsigned short)rv[j]);
        float* op = out + (size_t)n * HD + d0;
        *(float4*)op = make_float4(o[0], o[1], o[2], o[3]);
        *(float4*)(op + 4) = make_float4(o[4], o[5], o[6], o[7]);
    }
}

extern "C" void kernel_launch(void* const* d_in, const int* in_sizes, int n_in,
                              void* d_out, int out_size, void* d_ws, size_t ws_size,
                              hipStream_t stream) {
    const float* feat   = (const float*)d_in[0];
    const int*   src    = (const int*)d_in[1];
    const int*   dst    = (const int*)d_in[2];
    const float* W_fc   = (const float*)d_in[3];
    const float* attn_l = (const float*)d_in[4];
    const float* attn_r = (const float*)d_in[5];
    const float* W_res  = (const float*)d_in[6];
    float* out = (float*)d_out;

    int N = in_sizes[0] / IN_F;   // 50000
    int E = in_sizes[1];          // 800000
    int nb = (N + 255) / 256;     // 196 (<= 256 for scan2)

    size_t off = 0;
    auto alloc = [&](size_t bytes) {
        size_t o = off;
        off = (off + bytes + 255) & ~(size_t)255;
        return o;
    };
    char* ws = (char*)d_ws;
    unsigned short* h16     = (unsigned short*)(ws + alloc((size_t)N * HD * 2));
    unsigned short* resid16 = (unsigned short*)(ws + alloc((size_t)N * HD * 2));
    __hip_bfloat16* w16     = (__hip_bfloat16*)(ws + alloc((size_t)2 * HD * IN_F * 2));
    unsigned short* ew16    = (unsigned short*)(ws + alloc((size_t)16 * IN_F * 2));
    float* el               = (float*)(ws + alloc((size_t)N * 4 * 4));
    float* er               = (float*)(ws + alloc((size_t)N * 4 * 4));
    int* out_cnt            = (int*)(ws + alloc((size_t)N * 4));
    int* deg                = (int*)(ws + alloc((size_t)N * 4));
    int* row_start          = (int*)(ws + alloc((size_t)(N + 1) * 4));
    int* bsum               = (int*)(ws + alloc((size_t)nb * 4));
    int* esrc               = (int*)(ws + alloc((size_t)E * 4));

    // runtime-adaptive chunk count: each chunk needs 2 uint16 rows of N
    size_t per_chunk = (size_t)4 * N;
    size_t avail = (ws_size > off + 4096) ? (ws_size - off - 4096) : 0;
    int C = (int)(avail / per_chunk);
    if (C > 128) C = 128;
    if (C < 32) C = 32;           // round-6 footprint proved safe
    unsigned short* pc_dst = (unsigned short*)(ws + alloc((size_t)C * N * 2));
    unsigned short* pc_src = (unsigned short*)(ws + alloc((size_t)C * N * 2));
    int chunk = (E + C - 1) / C;

    int n4each = HD * IN_F / 4;
    cvt_w_kernel<<<(2 * n4each + 255) / 256, 256, 0, stream>>>(
        (const float4*)W_fc, (const float4*)W_res, (ushort4*)w16, n4each);
    ew_kernel<<<4, 256, 0, stream>>>(W_fc, attn_l, attn_r, ew16);

    hist_kernel<<<dim3(C, 2), 512, 0, stream>>>(src, dst, pc_src, pc_dst, N, E, chunk);
    sum_scan1_kernel<<<nb, 256, 0, stream>>>(pc_src, pc_dst, out_cnt, deg, bsum, N, C);
    scan2_kernel<<<1, 256, 0, stream>>>(bsum, nb, row_start + N, E);
    scan3_kernel<<<nb, 256, 0, stream>>>(deg, bsum, row_start, N);
    place_kernel<<<C, 512, 0, stream>>>(src, dst, pc_dst, row_start, esrc, N, E, chunk);

    gemm_fused<<<(N + 31) / 32, 256, 0, stream>>>(feat, (const __hip_bfloat16*)w16,
                                                  (const __hip_bfloat16*)ew16, out_cnt,
                                                  h16, resid16, el, er, N);

    int nb4 = (N + 3) / 4;
    agg_kernel<<<nb4, 256, 0, stream>>>(h16, el, er, row_start, esrc, resid16, out, N);
}

// Round 12
// 153.985 us; speedup vs baseline: 1.1210x; 1.0301x over previous
//
#include <hip/hip_runtime.h>
#include <hip/hip_bf16.h>
#include <math.h>

#define HD 128          // N_HEADS * OUT_FEATS
#define IN_F 256
#define NEG_SLOPE 0.2f
#define NMAX 50000      // problem-fixed node count (LDS histogram capacity)
#define GB 512          // persistent gemm grid

typedef __attribute__((ext_vector_type(8))) short short8;
typedef __attribute__((ext_vector_type(4))) float f32x4;

__device__ __forceinline__ unsigned short f2bf(float x) {
    __hip_bfloat16 b = __float2bfloat16(x);
    return *(unsigned short*)&b;
}
__device__ __forceinline__ float bf2f(unsigned short u) {
    unsigned int v = ((unsigned int)u) << 16;
    float f;
    __builtin_memcpy(&f, &v, 4);
    return f;
}
__device__ __forceinline__ short8 pack8(float4 f0, float4 f1) {
    short8 v;
    v[0] = (short)f2bf(f0.x); v[1] = (short)f2bf(f0.y);
    v[2] = (short)f2bf(f0.z); v[3] = (short)f2bf(f0.w);
    v[4] = (short)f2bf(f1.x); v[5] = (short)f2bf(f1.y);
    v[6] = (short)f2bf(f1.z); v[7] = (short)f2bf(f1.w);
    return v;
}

// ---------------- weights f32 -> bf16 ----------------
__global__ void cvt_w_kernel(const float4* __restrict__ wfc, const float4* __restrict__ wres,
                             ushort4* __restrict__ w16, int n4each) {
    int idx = blockIdx.x * blockDim.x + threadIdx.x;
    if (idx >= 2 * n4each) return;
    float4 f = (idx < n4each) ? wfc[idx] : wres[idx - n4each];
    ushort4 u;
    u.x = f2bf(f.x); u.y = f2bf(f.y); u.z = f2bf(f.z); u.w = f2bf(f.w);
    w16[idx] = u;
}

// ---------------- attention-projection columns: ew16[16][256] ----------------
// rows 0-3: al_w[h][k] = sum_d attn_l[h,d]*W_fc[h*32+d][k]; rows 4-7: ar_w; 8-15: 0.
__global__ __launch_bounds__(256) void ew_kernel(const float* __restrict__ wfc,
                                                 const float* __restrict__ attn_l,
                                                 const float* __restrict__ attn_r,
                                                 unsigned short* __restrict__ ew16) {
    int h = blockIdx.x;          // 4 blocks
    int k = threadIdx.x;         // 256
    float sl = 0.f, sr = 0.f;
#pragma unroll 8
    for (int d = 0; d < 32; d++) {
        float w = wfc[(size_t)(h * 32 + d) * IN_F + k];
        sl += attn_l[h * 32 + d] * w;
        sr += attn_r[h * 32 + d] * w;
    }
    ew16[h * IN_F + k] = f2bf(sl);
    ew16[(4 + h) * IN_F + k] = f2bf(sr);
    ew16[(8 + h) * IN_F + k] = 0;
    ew16[(12 + h) * IN_F + k] = 0;
}

// ---------------- per-chunk LDS histogram (uint16-packed, no global atomics) ----
__global__ __launch_bounds__(512) void hist_kernel(const int* __restrict__ src,
                                                   const int* __restrict__ dst,
                                                   unsigned short* __restrict__ pc_src,
                                                   unsigned short* __restrict__ pc_dst,
                                                   int N, int E, int chunk) {
    __shared__ unsigned int h[NMAX / 2];   // 100 KB packed uint16 counts
    int tid = threadIdx.x;
    int nh = N >> 1;                        // N even
    uint4* h4 = (uint4*)h;
    for (int i = tid; i < (nh >> 2); i += 512) h4[i] = make_uint4(0, 0, 0, 0);
    for (int i = (nh & ~3) + tid; i < nh; i += 512) h[i] = 0;
    __syncthreads();

    const int* arr = blockIdx.y ? src : dst;
    int e1 = min(E, (int)(blockIdx.x + 1) * chunk);
    for (int e = blockIdx.x * chunk + tid; e < e1; e += 512) {
        int v = arr[e];
        atomicAdd(&h[v >> 1], 1u << ((v & 1) << 4));
    }
    __syncthreads();

    unsigned short* pc = (blockIdx.y ? pc_src : pc_dst) + (size_t)blockIdx.x * N;
    uint4* pc4 = (uint4*)pc;
    for (int i = tid; i < (nh >> 2); i += 512) pc4[i] = h4[i];
    for (int i = (nh & ~3) + tid; i < nh; i += 512) ((unsigned int*)pc)[i] = h[i];
}

// ---------------- per-node chunk prefix (in place) + degrees + scan1 ----------------
__global__ __launch_bounds__(256) void sum_scan1_kernel(
    const unsigned short* __restrict__ pc_src, unsigned short* __restrict__ pc_dst,
    int* __restrict__ out_cnt, int* __restrict__ deg, int* __restrict__ bsum,
    int N, int C) {
    __shared__ int wsum[4];
    int n = blockIdx.x * 256 + threadIdx.x;
    int sd = 0;
    if (n < N) {
        int ss = 0;
        for (int c = 0; c < C; c++) {
            ss += pc_src[(size_t)c * N + n];
            unsigned short v = pc_dst[(size_t)c * N + n];
            pc_dst[(size_t)c * N + n] = (unsigned short)sd;  // exclusive chunk prefix
            sd += v;
        }
        out_cnt[n] = ss;
        deg[n] = sd;
    }
    int v = (n < N) ? sd : 0;
#pragma unroll
    for (int d = 1; d < 64; d <<= 1) v += __shfl_xor(v, d);
    if ((threadIdx.x & 63) == 0) wsum[threadIdx.x >> 6] = v;
    __syncthreads();
    if (threadIdx.x == 0) bsum[blockIdx.x] = wsum[0] + wsum[1] + wsum[2] + wsum[3];
}

// ---------------- scan of block sums ----------------
__global__ __launch_bounds__(256) void scan2_kernel(int* __restrict__ bsum, int nb,
                                                    int* __restrict__ row_start_N, int E) {
    __shared__ int wtot[4];
    int tid = threadIdx.x, lane = tid & 63, wid = tid >> 6;
    int v = (tid < nb) ? bsum[tid] : 0;
    int incl = v;
#pragma unroll
    for (int d = 1; d < 64; d <<= 1) {
        int t = __shfl_up(incl, d);
        if (lane >= d) incl += t;
    }
    if (lane == 63) wtot[wid] = incl;
    __syncthreads();
    int woff = 0;
    for (int w = 0; w < wid; w++) woff += wtot[w];
    if (tid < nb) bsum[tid] = woff + incl - v;  // exclusive block offset, in place
    if (tid == 0) *row_start_N = E;             // row_start[N]
}

__global__ __launch_bounds__(256) void scan3_kernel(const int* __restrict__ deg,
                                                    const int* __restrict__ boff,
                                                    int* __restrict__ row_start, int N) {
    __shared__ int wsum[4];
    int i = blockIdx.x * 256 + threadIdx.x;
    int lane = threadIdx.x & 63, wid = threadIdx.x >> 6;
    int v = (i < N) ? deg[i] : 0;
    int incl = v;
#pragma unroll
    for (int d = 1; d < 64; d <<= 1) {
        int t = __shfl_up(incl, d);
        if (lane >= d) incl += t;
    }
    if (lane == 63) wsum[wid] = incl;
    __syncthreads();
    int woff = 0;
    for (int w = 0; w < wid; w++) woff += wsum[w];
    int excl = boff[blockIdx.x] + woff + incl - v;
    if (i < N) row_start[i] = excl;
}

// ---------------- placement: LDS cursors seeded from chunk prefix ----------------
__global__ __launch_bounds__(512) void place_kernel(const int* __restrict__ src,
                                                    const int* __restrict__ dst,
                                                    const unsigned short* __restrict__ chunkpre,
                                                    const int* __restrict__ row_start,
                                                    int* __restrict__ esrc,
                                                    int N, int E, int chunk) {
    __shared__ unsigned int cur[NMAX / 2];   // packed uint16 cursors
    int tid = threadIdx.x;
    int nh = N >> 1;
    const unsigned short* cp = chunkpre + (size_t)blockIdx.x * N;
    const uint4* cp4 = (const uint4*)cp;
    uint4* cur4 = (uint4*)cur;
    for (int i = tid; i < (nh >> 2); i += 512) cur4[i] = cp4[i];
    for (int i = (nh & ~3) + tid; i < nh; i += 512) cur[i] = ((const unsigned int*)cp)[i];
    __syncthreads();

    int e1 = min(E, (int)(blockIdx.x + 1) * chunk);
    for (int e = blockIdx.x * chunk + tid; e < e1; e += 512) {
        int d = dst[e], s = src[e];
        int sh = (d & 1) << 4;
        unsigned int old = atomicAdd(&cur[d >> 1], 1u << sh);
        int rank = (old >> sh) & 0xffff;
        esrc[row_start[d] + rank] = s;
    }
}

// ---------------- persistent fused GEMM: corrected software pipeline ----------------
// 512 blocks x 4 waves; wave wn owns cols wn*64..+63. B panel in regs (whole
// kernel). Per tile: ONE barrier; prefetch issued AFTER the barrier so its
// waitcnt lands at the convert step (after k-loop + epilogue) -> L3 latency
// hidden under compute. el/er come from the ew16 B-fragment (wave 0).
__global__ __launch_bounds__(256, 2) void gemm_fused(
    const float* __restrict__ feat, const __hip_bfloat16* __restrict__ w16,
    const __hip_bfloat16* __restrict__ ew16, const int* __restrict__ out_cnt,
    unsigned short* __restrict__ h16, unsigned short* __restrict__ resid16,
    float* __restrict__ el, float* __restrict__ er, int N, int ntiles) {
    __shared__ unsigned short sA[2][32 * 256];  // 2 x 16 KiB, XOR-swizzled granules
    int tid = threadIdx.x;
    int lane = tid & 63, wn = tid >> 6;
    int l15 = lane & 15, lg = lane >> 4;
    int colbase = wn * 64;
    bool w0 = (wn == 0);
    bool isH = (wn < 2);
    int colloc = colbase & 127;

    // ---- B panel in regs: 4 col-frags x 8 k-steps ----
    short8 breg[4][8];
#pragma unroll
    for (int ni = 0; ni < 4; ni++) {
        const __hip_bfloat16* bp = w16 + (size_t)(colbase + ni * 16 + l15) * IN_F + lg * 8;
#pragma unroll
        for (int kk = 0; kk < 8; kk++) breg[ni][kk] = *(const short8*)(bp + kk * 32);
    }
    short8 ereg[8];
    {
        const __hip_bfloat16* ep = ew16 + (size_t)l15 * IN_F + lg * 8;
#pragma unroll
        for (int kk = 0; kk < 8; kk++) ereg[kk] = *(const short8*)(ep + kk * 32);
    }

    // stage mapping: granule G = i*256+tid -> row G>>5, 8-col group G&31
    int srow[4], sgc[4];
#pragma unroll
    for (int i = 0; i < 4; i++) {
        int G = i * 256 + tid;
        srow[i] = G >> 5;
        sgc[i] = G & 31;
    }

    float4 fA[4][2];
    int t = blockIdx.x;
    // prologue: load + convert tile t into buf 0
#pragma unroll
    for (int i = 0; i < 4; i++) {
        int gm = t * 32 + srow[i];
        gm = (gm < N) ? gm : (N - 1);
        const float4* fp = (const float4*)(feat + (size_t)gm * IN_F + sgc[i] * 8);
        fA[i][0] = fp[0];
        fA[i][1] = fp[1];
    }
#pragma unroll
    for (int i = 0; i < 4; i++)
        *(short8*)&sA[0][srow[i] * 256 + ((sgc[i] ^ (srow[i] & 7)) * 8)] =
            pack8(fA[i][0], fA[i][1]);

    int cur = 0;
    for (; t < ntiles; t += GB) {
        __syncthreads();   // sA[cur] writes visible to all waves

        // ---- issue next tile's loads AFTER the barrier (stay in flight) ----
        int tn = t + GB;
        if (tn < ntiles) {
#pragma unroll
            for (int i = 0; i < 4; i++) {
                int gm = tn * 32 + srow[i];
                gm = (gm < N) ? gm : (N - 1);
                const float4* fp = (const float4*)(feat + (size_t)gm * IN_F + sgc[i] * 8);
                fA[i][0] = fp[0];
                fA[i][1] = fp[1];
            }
        }

        // ---- k-loop: pure ds_read + MFMA (B in regs) ----
        f32x4 acc[2][4], accE[2];
#pragma unroll
        for (int i = 0; i < 2; i++) {
            accE[i] = (f32x4){0.f, 0.f, 0.f, 0.f};
#pragma unroll
            for (int j = 0; j < 4; j++) acc[i][j] = (f32x4){0.f, 0.f, 0.f, 0.f};
        }
#pragma unroll
        for (int kk = 0; kk < 8; kk++) {
            short8 a[2];
#pragma unroll
            for (int mi = 0; mi < 2; mi++) {
                int row = mi * 16 + l15;
                int gs = (kk * 4 + lg) ^ (row & 7);
                a[mi] = *(const short8*)&sA[cur][row * 256 + gs * 8];
            }
#pragma unroll
            for (int mi = 0; mi < 2; mi++)
#pragma unroll
                for (int ni = 0; ni < 4; ni++)
                    acc[mi][ni] = __builtin_amdgcn_mfma_f32_16x16x32_bf16(
                        a[mi], breg[ni][kk], acc[mi][ni], 0, 0, 0);
            if (w0) {
#pragma unroll
                for (int mi = 0; mi < 2; mi++)
                    accE[mi] = __builtin_amdgcn_mfma_f32_16x16x32_bf16(
                        a[mi], ereg[kk], accE[mi], 0, 0, 0);
            }
        }

        // ---- epilogue tile t. C/D: col = lane&15, row = 4*(lane>>4)+reg ----
        int bm = t * 32;
#pragma unroll
        for (int mi = 0; mi < 2; mi++) {
#pragma unroll
            for (int reg = 0; reg < 4; reg++) {
                int r = bm + mi * 16 + lg * 4 + reg;
                bool valid = (r < N);
                int rr = valid ? r : 0;
                if (isH) {
                    float nrm = rsqrtf(fmaxf((float)out_cnt[rr], 1.0f));
                    if (valid) {
#pragma unroll
                        for (int ni = 0; ni < 4; ni++)
                            h16[(size_t)r * HD + colloc + ni * 16 + l15] =
                                f2bf(acc[mi][ni][reg] * nrm);
                        if (w0) {
                            float ev = accE[mi][reg];  // l15<4: el, 4..7: er
                            if (l15 < 4) el[r * 4 + l15] = ev * nrm;
                            else if (l15 < 8) er[r * 4 + (l15 - 4)] = ev;
                        }
                    }
                } else if (valid) {
#pragma unroll
                    for (int ni = 0; ni < 4; ni++)
                        resid16[(size_t)r * HD + colloc + ni * 16 + l15] =
                            f2bf(acc[mi][ni][reg]);
                }
            }
        }

        // ---- convert prefetched regs into the other buffer (waitcnt lands here) ----
        if (tn < ntiles) {
#pragma unroll
            for (int i = 0; i < 4; i++)
                *(short8*)&sA[cur ^ 1][srow[i] * 256 + ((sgc[i] ^ (srow[i] & 7)) * 8)] =
                    pack8(fA[i][0], fA[i][1]);
        }
        cur ^= 1;
    }
}

// ---------------- fused edge softmax + weighted scatter + final ----------------
// One wave per dst node, lane-transposed: 64 lanes = 4 edge-slots x 16 dim-lanes.
// 2-stage software pipeline; final write = sc*acc + resid16 (out written once).
__global__ __launch_bounds__(256) void agg_kernel(const unsigned short* __restrict__ h16,
                                                  const float* __restrict__ el,
                                                  const float* __restrict__ er,
                                                  const int* __restrict__ row_start,
                                                  const int* __restrict__ esrc,
                                                  const unsigned short* __restrict__ resid16,
                                                  float* __restrict__ out, int N) {
    int wid = threadIdx.x >> 6, lane = threadIdx.x & 63;
    int n = blockIdx.x * 4 + wid;
    if (n >= N) return;
    int es = lane >> 4;        // edge slot 0..3
    int l15 = lane & 15;
    int h = l15 >> 2;          // head owning this lane's 8 dims
    int d0 = l15 * 8;
    int beg = row_start[n], end = row_start[n + 1];
    float erh = er[n * 4 + h];
    float den = 0.f;
    float acc[8];
#pragma unroll
    for (int j = 0; j < 8; j++) acc[j] = 0.f;

    if (beg < end) {
        bool ok0, ok1;
        float ev0, ev1; short8 hv0, hv1;
        {
            int i0 = beg + es, i1 = beg + 4 + es;
            ok0 = i0 < end; ok1 = i1 < end;
            int s0 = esrc[ok0 ? i0 : beg];
            int s1 = esrc[ok1 ? i1 : beg];
            ev0 = el[s0 * 4 + h]; ev1 = el[s1 * 4 + h];
            hv0 = *(const short8*)(h16 + (size_t)s0 * HD + d0);
            hv1 = *(const short8*)(h16 + (size_t)s1 * HD + d0);
        }
        for (int base = beg + 8; base < end; base += 8) {
            int i0 = base + es, i1 = base + 4 + es;
            bool p0 = i0 < end, p1 = i1 < end;
            int t0 = esrc[p0 ? i0 : beg];
            int t1 = esrc[p1 ? i1 : beg];
            float fv0 = el[t0 * 4 + h];
            float fv1 = el[t1 * 4 + h];
            short8 g0 = *(const short8*)(h16 + (size_t)t0 * HD + d0);
            short8 g1 = *(const short8*)(h16 + (size_t)t1 * HD + d0);
            float e0 = ev0 + erh; e0 = (e0 > 0.f) ? e0 : NEG_SLOPE * e0;
            float e1 = ev1 + erh; e1 = (e1 > 0.f) ? e1 : NEG_SLOPE * e1;
            float ex0 = ok0 ? __expf(e0) : 0.f;
            float ex1 = ok1 ? __expf(e1) : 0.f;
            den += ex0 + ex1;
#pragma unroll
            for (int j = 0; j < 8; j++)
                acc[j] += ex0 * bf2f((unsigned short)hv0[j]) +
                          ex1 * bf2f((unsigned short)hv1[j]);
            ok0 = p0; ok1 = p1; ev0 = fv0; ev1 = fv1; hv0 = g0; hv1 = g1;
        }
        float e0 = ev0 + erh; e0 = (e0 > 0.f) ? e0 : NEG_SLOPE * e0;
        float e1 = ev1 + erh; e1 = (e1 > 0.f) ? e1 : NEG_SLOPE * e1;
        float ex0 = ok0 ? __expf(e0) : 0.f;
        float ex1 = ok1 ? __expf(e1) : 0.f;
        den += ex0 + ex1;
#pragma unroll
        for (int j = 0; j < 8; j++)
            acc[j] += ex0 * bf2f((unsigned short)hv0[j]) +
                      ex1 * bf2f((unsigned short)hv1[j]);
    }

#pragma unroll
    for (int m = 16; m < 64; m <<= 1) {
        den += __shfl_xor(den, m);
#pragma unroll
        for (int j = 0; j < 8; j++) acc[j] += __shfl_xor(acc[j], m);
    }

    if (es == 0) {
        const unsigned short* rp = resid16 + (size_t)n * HD + d0;
        short8 rv = *(const short8*)rp;
        int indeg = end - beg;
        float sc = (indeg > 0) ? sqrtf((float)indeg) / den : 0.f;
        float o[8];
#pragma unroll
        for (int j = 0; j < 8; j++)
            o[j] = sc * acc[j] + bf2f((unsigned short)rv[j]);
        float* op = out + (size_t)n * HD + d0;
        *(float4*)op = make_float4(o[0], o[1], o[2], o[3]);
        *(float4*)(op + 4) = make_float4(o[4], o[5], o[6], o[7]);
    }
}

extern "C" void kernel_launch(void* const* d_in, const int* in_sizes, int n_in,
                              void* d_out, int out_size, void* d_ws, size_t ws_size,
                              hipStream_t stream) {
    const float* feat   = (const float*)d_in[0];
    const int*   src    = (const int*)d_in[1];
    const int*   dst    = (const int*)d_in[2];
    const float* W_fc   = (const float*)d_in[3];
    const float* attn_l = (const float*)d_in[4];
    const float* attn_r = (const float*)d_in[5];
    const float* W_res  = (const float*)d_in[6];
    float* out = (float*)d_out;

    int N = in_sizes[0] / IN_F;   // 50000
    int E = in_sizes[1];          // 800000
    int nb = (N + 255) / 256;     // 196 (<= 256 for scan2)

    size_t off = 0;
    auto alloc = [&](size_t bytes) {
        size_t o = off;
        off = (off + bytes + 255) & ~(size_t)255;
        return o;
    };
    char* ws = (char*)d_ws;
    unsigned short* h16     = (unsigned short*)(ws + alloc((size_t)N * HD * 2));
    unsigned short* resid16 = (unsigned short*)(ws + alloc((size_t)N * HD * 2));
    __hip_bfloat16* w16     = (__hip_bfloat16*)(ws + alloc((size_t)2 * HD * IN_F * 2));
    unsigned short* ew16    = (unsigned short*)(ws + alloc((size_t)16 * IN_F * 2));
    float* el               = (float*)(ws + alloc((size_t)N * 4 * 4));
    float* er               = (float*)(ws + alloc((size_t)N * 4 * 4));
    int* out_cnt            = (int*)(ws + alloc((size_t)N * 4));
    int* deg                = (int*)(ws + alloc((size_t)N * 4));
    int* row_start          = (int*)(ws + alloc((size_t)(N + 1) * 4));
    int* bsum               = (int*)(ws + alloc((size_t)nb * 4));
    int* esrc               = (int*)(ws + alloc((size_t)E * 4));

    // runtime-adaptive chunk count: each chunk needs 2 uint16 rows of N
    size_t per_chunk = (size_t)4 * N;
    size_t avail = (ws_size > off + 4096) ? (ws_size - off - 4096) : 0;
    int C = (int)(avail / per_chunk);
    if (C > 128) C = 128;
    if (C < 32) C = 32;           // round-6 footprint proved safe
    unsigned short* pc_dst = (unsigned short*)(ws + alloc((size_t)C * N * 2));
    unsigned short* pc_src = (unsigned short*)(ws + alloc((size_t)C * N * 2));
    int chunk = (E + C - 1) / C;

    int n4each = HD * IN_F / 4;
    cvt_w_kernel<<<(2 * n4each + 255) / 256, 256, 0, stream>>>(
        (const float4*)W_fc, (const float4*)W_res, (ushort4*)w16, n4each);
    ew_kernel<<<4, 256, 0, stream>>>(W_fc, attn_l, attn_r, ew16);

    hist_kernel<<<dim3(C, 2), 512, 0, stream>>>(src, dst, pc_src, pc_dst, N, E, chunk);
    sum_scan1_kernel<<<nb, 256, 0, stream>>>(pc_src, pc_dst, out_cnt, deg, bsum, N, C);
    scan2_kernel<<<1, 256, 0, stream>>>(bsum, nb, row_start + N, E);
    scan3_kernel<<<nb, 256, 0, stream>>>(deg, bsum, row_start, N);
    place_kernel<<<C, 512, 0, stream>>>(src, dst, pc_dst, row_start, esrc, N, E, chunk);

    int ntiles = (N + 31) / 32;
    gemm_fused<<<GB, 256, 0, stream>>>(feat, (const __hip_bfloat16*)w16,
                                       (const __hip_bfloat16*)ew16, out_cnt,
                                       h16, resid16, el, er, N, ntiles);

    int nb4 = (N + 3) / 4;
    agg_kernel<<<nb4, 256, 0, stream>>>(h16, el, er, row_start, esrc, resid16, out, N);
}

// Round 13
// 153.746 us; speedup vs baseline: 1.1228x; 1.0016x over previous
//
#include <hip/hip_runtime.h>
#include <hip/hip_bf16.h>
#include <math.h>

#define HD 128          // N_HEADS * OUT_FEATS
#define IN_F 256
#define NEG_SLOPE 0.2f
#define NMAX 50000      // problem-fixed node count (LDS histogram capacity)
#define GB 512          // persistent gemm grid

typedef __attribute__((ext_vector_type(8))) short short8;
typedef __attribute__((ext_vector_type(4))) float f32x4;

__device__ __forceinline__ unsigned short f2bf(float x) {
    __hip_bfloat16 b = __float2bfloat16(x);
    return *(unsigned short*)&b;
}
__device__ __forceinline__ float bf2f(unsigned short u) {
    unsigned int v = ((unsigned int)u) << 16;
    float f;
    __builtin_memcpy(&f, &v, 4);
    return f;
}
__device__ __forceinline__ short8 pack8(float4 f0, float4 f1) {
    short8 v;
    v[0] = (short)f2bf(f0.x); v[1] = (short)f2bf(f0.y);
    v[2] = (short)f2bf(f0.z); v[3] = (short)f2bf(f0.w);
    v[4] = (short)f2bf(f1.x); v[5] = (short)f2bf(f1.y);
    v[6] = (short)f2bf(f1.z); v[7] = (short)f2bf(f1.w);
    return v;
}

// ---------------- weights f32 -> bf16 ----------------
__global__ void cvt_w_kernel(const float4* __restrict__ wfc, const float4* __restrict__ wres,
                             ushort4* __restrict__ w16, int n4each) {
    int idx = blockIdx.x * blockDim.x + threadIdx.x;
    if (idx >= 2 * n4each) return;
    float4 f = (idx < n4each) ? wfc[idx] : wres[idx - n4each];
    ushort4 u;
    u.x = f2bf(f.x); u.y = f2bf(f.y); u.z = f2bf(f.z); u.w = f2bf(f.w);
    w16[idx] = u;
}

// ---------------- attention-projection columns: ew16[16][256] ----------------
// rows 0-3: al_w[h][k] = sum_d attn_l[h,d]*W_fc[h*32+d][k]; rows 4-7: ar_w; 8-15: 0.
__global__ __launch_bounds__(256) void ew_kernel(const float* __restrict__ wfc,
                                                 const float* __restrict__ attn_l,
                                                 const float* __restrict__ attn_r,
                                                 unsigned short* __restrict__ ew16) {
    int h = blockIdx.x;          // 4 blocks
    int k = threadIdx.x;         // 256
    float sl = 0.f, sr = 0.f;
#pragma unroll 8
    for (int d = 0; d < 32; d++) {
        float w = wfc[(size_t)(h * 32 + d) * IN_F + k];
        sl += attn_l[h * 32 + d] * w;
        sr += attn_r[h * 32 + d] * w;
    }
    ew16[h * IN_F + k] = f2bf(sl);
    ew16[(4 + h) * IN_F + k] = f2bf(sr);
    ew16[(8 + h) * IN_F + k] = 0;
    ew16[(12 + h) * IN_F + k] = 0;
}

// ---------------- per-chunk LDS histogram (uint16-packed, no global atomics) ----
__global__ __launch_bounds__(512) void hist_kernel(const int* __restrict__ src,
                                                   const int* __restrict__ dst,
                                                   unsigned short* __restrict__ pc_src,
                                                   unsigned short* __restrict__ pc_dst,
                                                   int N, int E, int chunk) {
    __shared__ unsigned int h[NMAX / 2];   // 100 KB packed uint16 counts
    int tid = threadIdx.x;
    int nh = N >> 1;                        // N even
    uint4* h4 = (uint4*)h;
    for (int i = tid; i < (nh >> 2); i += 512) h4[i] = make_uint4(0, 0, 0, 0);
    for (int i = (nh & ~3) + tid; i < nh; i += 512) h[i] = 0;
    __syncthreads();

    const int* arr = blockIdx.y ? src : dst;
    int e1 = min(E, (int)(blockIdx.x + 1) * chunk);
    for (int e = blockIdx.x * chunk + tid; e < e1; e += 512) {
        int v = arr[e];
        atomicAdd(&h[v >> 1], 1u << ((v & 1) << 4));
    }
    __syncthreads();

    unsigned short* pc = (blockIdx.y ? pc_src : pc_dst) + (size_t)blockIdx.x * N;
    uint4* pc4 = (uint4*)pc;
    for (int i = tid; i < (nh >> 2); i += 512) pc4[i] = h4[i];
    for (int i = (nh & ~3) + tid; i < nh; i += 512) ((unsigned int*)pc)[i] = h[i];
}

// ---------------- per-node chunk prefix (in place) + degrees + scan1 ----------------
__global__ __launch_bounds__(256) void sum_scan1_kernel(
    const unsigned short* __restrict__ pc_src, unsigned short* __restrict__ pc_dst,
    int* __restrict__ out_cnt, int* __restrict__ deg, int* __restrict__ bsum,
    int N, int C) {
    __shared__ int wsum[4];
    int n = blockIdx.x * 256 + threadIdx.x;
    int sd = 0;
    if (n < N) {
        int ss = 0;
        for (int c = 0; c < C; c++) {
            ss += pc_src[(size_t)c * N + n];
            unsigned short v = pc_dst[(size_t)c * N + n];
            pc_dst[(size_t)c * N + n] = (unsigned short)sd;  // exclusive chunk prefix
            sd += v;
        }
        out_cnt[n] = ss;
        deg[n] = sd;
    }
    int v = (n < N) ? sd : 0;
#pragma unroll
    for (int d = 1; d < 64; d <<= 1) v += __shfl_xor(v, d);
    if ((threadIdx.x & 63) == 0) wsum[threadIdx.x >> 6] = v;
    __syncthreads();
    if (threadIdx.x == 0) bsum[blockIdx.x] = wsum[0] + wsum[1] + wsum[2] + wsum[3];
}

// ---------------- scan of block sums ----------------
__global__ __launch_bounds__(256) void scan2_kernel(int* __restrict__ bsum, int nb,
                                                    int* __restrict__ row_start_N, int E) {
    __shared__ int wtot[4];
    int tid = threadIdx.x, lane = tid & 63, wid = tid >> 6;
    int v = (tid < nb) ? bsum[tid] : 0;
    int incl = v;
#pragma unroll
    for (int d = 1; d < 64; d <<= 1) {
        int t = __shfl_up(incl, d);
        if (lane >= d) incl += t;
    }
    if (lane == 63) wtot[wid] = incl;
    __syncthreads();
    int woff = 0;
    for (int w = 0; w < wid; w++) woff += wtot[w];
    if (tid < nb) bsum[tid] = woff + incl - v;  // exclusive block offset, in place
    if (tid == 0) *row_start_N = E;             // row_start[N]
}

__global__ __launch_bounds__(256) void scan3_kernel(const int* __restrict__ deg,
                                                    const int* __restrict__ boff,
                                                    int* __restrict__ row_start, int N) {
    __shared__ int wsum[4];
    int i = blockIdx.x * 256 + threadIdx.x;
    int lane = threadIdx.x & 63, wid = threadIdx.x >> 6;
    int v = (i < N) ? deg[i] : 0;
    int incl = v;
#pragma unroll
    for (int d = 1; d < 64; d <<= 1) {
        int t = __shfl_up(incl, d);
        if (lane >= d) incl += t;
    }
    if (lane == 63) wsum[wid] = incl;
    __syncthreads();
    int woff = 0;
    for (int w = 0; w < wid; w++) woff += wsum[w];
    int excl = boff[blockIdx.x] + woff + incl - v;
    if (i < N) row_start[i] = excl;
}

// ---------------- placement: LDS cursors seeded from chunk prefix ----------------
__global__ __launch_bounds__(512) void place_kernel(const int* __restrict__ src,
                                                    const int* __restrict__ dst,
                                                    const unsigned short* __restrict__ chunkpre,
                                                    const int* __restrict__ row_start,
                                                    int* __restrict__ esrc,
                                                    int N, int E, int chunk) {
    __shared__ unsigned int cur[NMAX / 2];   // packed uint16 cursors
    int tid = threadIdx.x;
    int nh = N >> 1;
    const unsigned short* cp = chunkpre + (size_t)blockIdx.x * N;
    const uint4* cp4 = (const uint4*)cp;
    uint4* cur4 = (uint4*)cur;
    for (int i = tid; i < (nh >> 2); i += 512) cur4[i] = cp4[i];
    for (int i = (nh & ~3) + tid; i < nh; i += 512) cur[i] = ((const unsigned int*)cp)[i];
    __syncthreads();

    int e1 = min(E, (int)(blockIdx.x + 1) * chunk);
    for (int e = blockIdx.x * chunk + tid; e < e1; e += 512) {
        int d = dst[e], s = src[e];
        int sh = (d & 1) << 4;
        unsigned int old = atomicAdd(&cur[d >> 1], 1u << sh);
        int rank = (old >> sh) & 0xffff;
        esrc[row_start[d] + rank] = s;
    }
}

// ---------------- persistent fused GEMM: corrected software pipeline ----------------
// 512 blocks x 4 waves; wave wn owns cols wn*64..+63. B panel in regs (whole
// kernel). Per tile: ONE barrier; prefetch issued AFTER the barrier so its
// waitcnt lands at the convert step (after k-loop + epilogue) -> L3 latency
// hidden under compute. el/er come from the ew16 B-fragment (wave 0).
__global__ __launch_bounds__(256, 2) void gemm_fused(
    const float* __restrict__ feat, const __hip_bfloat16* __restrict__ w16,
    const __hip_bfloat16* __restrict__ ew16, const int* __restrict__ out_cnt,
    unsigned short* __restrict__ h16, unsigned short* __restrict__ resid16,
    float* __restrict__ el, float* __restrict__ er, int N, int ntiles) {
    __shared__ unsigned short sA[2][32 * 256];  // 2 x 16 KiB, XOR-swizzled granules
    int tid = threadIdx.x;
    int lane = tid & 63, wn = tid >> 6;
    int l15 = lane & 15, lg = lane >> 4;
    int colbase = wn * 64;
    bool w0 = (wn == 0);
    bool isH = (wn < 2);
    int colloc = colbase & 127;

    // ---- B panel in regs: 4 col-frags x 8 k-steps ----
    short8 breg[4][8];
#pragma unroll
    for (int ni = 0; ni < 4; ni++) {
        const __hip_bfloat16* bp = w16 + (size_t)(colbase + ni * 16 + l15) * IN_F + lg * 8;
#pragma unroll
        for (int kk = 0; kk < 8; kk++) breg[ni][kk] = *(const short8*)(bp + kk * 32);
    }
    short8 ereg[8];
    {
        const __hip_bfloat16* ep = ew16 + (size_t)l15 * IN_F + lg * 8;
#pragma unroll
        for (int kk = 0; kk < 8; kk++) ereg[kk] = *(const short8*)(ep + kk * 32);
    }

    // stage mapping: granule G = i*256+tid -> row G>>5, 8-col group G&31
    int srow[4], sgc[4];
#pragma unroll
    for (int i = 0; i < 4; i++) {
        int G = i * 256 + tid;
        srow[i] = G >> 5;
        sgc[i] = G & 31;
    }

    float4 fA[4][2];
    int t = blockIdx.x;
    // prologue: load + convert tile t into buf 0
#pragma unroll
    for (int i = 0; i < 4; i++) {
        int gm = t * 32 + srow[i];
        gm = (gm < N) ? gm : (N - 1);
        const float4* fp = (const float4*)(feat + (size_t)gm * IN_F + sgc[i] * 8);
        fA[i][0] = fp[0];
        fA[i][1] = fp[1];
    }
#pragma unroll
    for (int i = 0; i < 4; i++)
        *(short8*)&sA[0][srow[i] * 256 + ((sgc[i] ^ (srow[i] & 7)) * 8)] =
            pack8(fA[i][0], fA[i][1]);

    int cur = 0;
    for (; t < ntiles; t += GB) {
        __syncthreads();   // sA[cur] writes visible to all waves

        // ---- issue next tile's loads AFTER the barrier (stay in flight) ----
        int tn = t + GB;
        if (tn < ntiles) {
#pragma unroll
            for (int i = 0; i < 4; i++) {
                int gm = tn * 32 + srow[i];
                gm = (gm < N) ? gm : (N - 1);
                const float4* fp = (const float4*)(feat + (size_t)gm * IN_F + sgc[i] * 8);
                fA[i][0] = fp[0];
                fA[i][1] = fp[1];
            }
        }

        // ---- k-loop: pure ds_read + MFMA (B in regs) ----
        f32x4 acc[2][4], accE[2];
#pragma unroll
        for (int i = 0; i < 2; i++) {
            accE[i] = (f32x4){0.f, 0.f, 0.f, 0.f};
#pragma unroll
            for (int j = 0; j < 4; j++) acc[i][j] = (f32x4){0.f, 0.f, 0.f, 0.f};
        }
#pragma unroll
        for (int kk = 0; kk < 8; kk++) {
            short8 a[2];
#pragma unroll
            for (int mi = 0; mi < 2; mi++) {
                int row = mi * 16 + l15;
                int gs = (kk * 4 + lg) ^ (row & 7);
                a[mi] = *(const short8*)&sA[cur][row * 256 + gs * 8];
            }
#pragma unroll
            for (int mi = 0; mi < 2; mi++)
#pragma unroll
                for (int ni = 0; ni < 4; ni++)
                    acc[mi][ni] = __builtin_amdgcn_mfma_f32_16x16x32_bf16(
                        a[mi], breg[ni][kk], acc[mi][ni], 0, 0, 0);
            if (w0) {
#pragma unroll
                for (int mi = 0; mi < 2; mi++)
                    accE[mi] = __builtin_amdgcn_mfma_f32_16x16x32_bf16(
                        a[mi], ereg[kk], accE[mi], 0, 0, 0);
            }
        }

        // ---- epilogue tile t. C/D: col = lane&15, row = 4*(lane>>4)+reg ----
        int bm = t * 32;
#pragma unroll
        for (int mi = 0; mi < 2; mi++) {
#pragma unroll
            for (int reg = 0; reg < 4; reg++) {
                int r = bm + mi * 16 + lg * 4 + reg;
                bool valid = (r < N);
                int rr = valid ? r : 0;
                if (isH) {
                    float nrm = rsqrtf(fmaxf((float)out_cnt[rr], 1.0f));
                    if (valid) {
#pragma unroll
                        for (int ni = 0; ni < 4; ni++)
                            h16[(size_t)r * HD + colloc + ni * 16 + l15] =
                                f2bf(acc[mi][ni][reg] * nrm);
                        if (w0) {
                            float ev = accE[mi][reg];  // l15<4: el, 4..7: er
                            if (l15 < 4) el[r * 4 + l15] = ev * nrm;
                            else if (l15 < 8) er[r * 4 + (l15 - 4)] = ev;
                        }
                    }
                } else if (valid) {
#pragma unroll
                    for (int ni = 0; ni < 4; ni++)
                        resid16[(size_t)r * HD + colloc + ni * 16 + l15] =
                            f2bf(acc[mi][ni][reg]);
                }
            }
        }

        // ---- convert prefetched regs into the other buffer (waitcnt lands here) ----
        if (tn < ntiles) {
#pragma unroll
            for (int i = 0; i < 4; i++)
                *(short8*)&sA[cur ^ 1][srow[i] * 256 + ((sgc[i] ^ (srow[i] & 7)) * 8)] =
                    pack8(fA[i][0], fA[i][1]);
        }
        cur ^= 1;
    }
}

// ---------------- fused edge softmax + weighted scatter + final ----------------
// One wave per dst node, lane-transposed: 64 lanes = 4 edge-slots x 16 dim-lanes.
// 2-stage software pipeline; final write = sc*acc + resid16 (out written once).
__global__ __launch_bounds__(256) void agg_kernel(const unsigned short* __restrict__ h16,
                                                  const float* __restrict__ el,
                                                  const float* __restrict__ er,
                                                  const int* __restrict__ row_start,
                                                  const int* __restrict__ esrc,
                                                  const unsigned short* __restrict__ resid16,
                                                  float* __restrict__ out, int N) {
    int wid = threadIdx.x >> 6, lane = threadIdx.x & 63;
    int n = blockIdx.x * 4 + wid;
    if (n >= N) return;
    int es = lane >> 4;        // edge slot 0..3
    int l15 = lane & 15;
    int h = l15 >> 2;          // head owning this lane's 8 dims
    int d0 = l15 * 8;
    int beg = row_start[n], end = row_start[n + 1];
    float erh = er[n * 4 + h];
    float den = 0.f;
    float acc[8];
#pragma unroll
    for (int j = 0; j < 8; j++) acc[j] = 0.f;

    if (beg < end) {
        bool ok0, ok1;
        float ev0, ev1; short8 hv0, hv1;
        {
            int i0 = beg + es, i1 = beg + 4 + es;
            ok0 = i0 < end; ok1 = i1 < end;
            int s0 = esrc[ok0 ? i0 : beg];
            int s1 = esrc[ok1 ? i1 : beg];
            ev0 = el[s0 * 4 + h]; ev1 = el[s1 * 4 + h];
            hv0 = *(const short8*)(h16 + (size_t)s0 * HD + d0);
            hv1 = *(const short8*)(h16 + (size_t)s1 * HD + d0);
        }
        for (int base = beg + 8; base < end; base += 8) {
            int i0 = base + es, i1 = base + 4 + es;
            bool p0 = i0 < end, p1 = i1 < end;
            int t0 = esrc[p0 ? i0 : beg];
            int t1 = esrc[p1 ? i1 : beg];
            float fv0 = el[t0 * 4 + h];
            float fv1 = el[t1 * 4 + h];
            short8 g0 = *(const short8*)(h16 + (size_t)t0 * HD + d0);
            short8 g1 = *(const short8*)(h16 + (size_t)t1 * HD + d0);
            float e0 = ev0 + erh; e0 = (e0 > 0.f) ? e0 : NEG_SLOPE * e0;
            float e1 = ev1 + erh; e1 = (e1 > 0.f) ? e1 : NEG_SLOPE * e1;
            float ex0 = ok0 ? __expf(e0) : 0.f;
            float ex1 = ok1 ? __expf(e1) : 0.f;
            den += ex0 + ex1;
#pragma unroll
            for (int j = 0; j < 8; j++)
                acc[j] += ex0 * bf2f((unsigned short)hv0[j]) +
                          ex1 * bf2f((unsigned short)hv1[j]);
            ok0 = p0; ok1 = p1; ev0 = fv0; ev1 = fv1; hv0 = g0; hv1 = g1;
        }
        float e0 = ev0 + erh; e0 = (e0 > 0.f) ? e0 : NEG_SLOPE * e0;
        float e1 = ev1 + erh; e1 = (e1 > 0.f) ? e1 : NEG_SLOPE * e1;
        float ex0 = ok0 ? __expf(e0) : 0.f;
        float ex1 = ok1 ? __expf(e1) : 0.f;
        den += ex0 + ex1;
#pragma unroll
        for (int j = 0; j < 8; j++)
            acc[j] += ex0 * bf2f((unsigned short)hv0[j]) +
                      ex1 * bf2f((unsigned short)hv1[j]);
    }

#pragma unroll
    for (int m = 16; m < 64; m <<= 1) {
        den += __shfl_xor(den, m);
#pragma unroll
        for (int j = 0; j < 8; j++) acc[j] += __shfl_xor(acc[j], m);
    }

    if (es == 0) {
        const unsigned short* rp = resid16 + (size_t)n * HD + d0;
        short8 rv = *(const short8*)rp;
        int indeg = end - beg;
        float sc = (indeg > 0) ? sqrtf((float)indeg) / den : 0.f;
        float o[8];
#pragma unroll
        for (int j = 0; j < 8; j++)
            o[j] = sc * acc[j] + bf2f((unsigned short)rv[j]);
        float* op = out + (size_t)n * HD + d0;
        *(float4*)op = make_float4(o[0], o[1], o[2], o[3]);
        *(float4*)(op + 4) = make_float4(o[4], o[5], o[6], o[7]);
    }
}

extern "C" void kernel_launch(void* const* d_in, const int* in_sizes, int n_in,
                              void* d_out, int out_size, void* d_ws, size_t ws_size,
                              hipStream_t stream) {
    const float* feat   = (const float*)d_in[0];
    const int*   src    = (const int*)d_in[1];
    const int*   dst    = (const int*)d_in[2];
    const float* W_fc   = (const float*)d_in[3];
    const float* attn_l = (const float*)d_in[4];
    const float* attn_r = (const float*)d_in[5];
    const float* W_res  = (const float*)d_in[6];
    float* out = (float*)d_out;

    int N = in_sizes[0] / IN_F;   // 50000
    int E = in_sizes[1];          // 800000
    int nb = (N + 255) / 256;     // 196 (<= 256 for scan2)

    size_t off = 0;
    auto alloc = [&](size_t bytes) {
        size_t o = off;
        off = (off + bytes + 255) & ~(size_t)255;
        return o;
    };
    char* ws = (char*)d_ws;
    unsigned short* h16     = (unsigned short*)(ws + alloc((size_t)N * HD * 2));
    unsigned short* resid16 = (unsigned short*)(ws + alloc((size_t)N * HD * 2));
    __hip_bfloat16* w16     = (__hip_bfloat16*)(ws + alloc((size_t)2 * HD * IN_F * 2));
    unsigned short* ew16    = (unsigned short*)(ws + alloc((size_t)16 * IN_F * 2));
    float* el               = (float*)(ws + alloc((size_t)N * 4 * 4));
    float* er               = (float*)(ws + alloc((size_t)N * 4 * 4));
    int* out_cnt            = (int*)(ws + alloc((size_t)N * 4));
    int* deg                = (int*)(ws + alloc((size_t)N * 4));
    int* row_start          = (int*)(ws + alloc((size_t)(N + 1) * 4));
    int* bsum               = (int*)(ws + alloc((size_t)nb * 4));
    int* esrc               = (int*)(ws + alloc((size_t)E * 4));

    // runtime-adaptive chunk count: each chunk needs 2 uint16 rows of N
    size_t per_chunk = (size_t)4 * N;
    size_t avail = (ws_size > off + 4096) ? (ws_size - off - 4096) : 0;
    int C = (int)(avail / per_chunk);
    if (C > 128) C = 128;
    if (C < 32) C = 32;           // round-6 footprint proved safe
    unsigned short* pc_dst = (unsigned short*)(ws + alloc((size_t)C * N * 2));
    unsigned short* pc_src = (unsigned short*)(ws + alloc((size_t)C * N * 2));
    int chunk = (E + C - 1) / C;

    int n4each = HD * IN_F / 4;
    cvt_w_kernel<<<(2 * n4each + 255) / 256, 256, 0, stream>>>(
        (const float4*)W_fc, (const float4*)W_res, (ushort4*)w16, n4each);
    ew_kernel<<<4, 256, 0, stream>>>(W_fc, attn_l, attn_r, ew16);

    hist_kernel<<<dim3(C, 2), 512, 0, stream>>>(src, dst, pc_src, pc_dst, N, E, chunk);
    sum_scan1_kernel<<<nb, 256, 0, stream>>>(pc_src, pc_dst, out_cnt, deg, bsum, N, C);
    scan2_kernel<<<1, 256, 0, stream>>>(bsum, nb, row_start + N, E);
    scan3_kernel<<<nb, 256, 0, stream>>>(deg, bsum, row_start, N);
    place_kernel<<<C, 512, 0, stream>>>(src, dst, pc_dst, row_start, esrc, N, E, chunk);

    int ntiles = (N + 31) / 32;
    gemm_fused<<<GB, 256, 0, stream>>>(feat, (const __hip_bfloat16*)w16,
                                       (const __hip_bfloat16*)ew16, out_cnt,
                                       h16, resid16, el, er, N, ntiles);

    int nb4 = (N + 3) / 4;
    agg_kernel<<<nb4, 256, 0, stream>>>(h16, el, er, row_start, esrc, resid16, out, N);
}

// Round 14
// 144.483 us; speedup vs baseline: 1.1948x; 1.0641x over previous
//
#include <hip/hip_runtime.h>
#include <hip/hip_bf16.h>
#include <math.h>

#define HD 128          // N_HEADS * OUT_FEATS
#define IN_F 256
#define NEG_SLOPE 0.2f
#define NMAX 50000      // problem-fixed node count (LDS histogram capacity)
#define GGRID 256       // persistent gemm grid (1 block/CU, 8 waves)

typedef __attribute__((ext_vector_type(8))) short short8;
typedef __attribute__((ext_vector_type(4))) float f32x4;

__device__ __forceinline__ unsigned short f2bf(float x) {
    __hip_bfloat16 b = __float2bfloat16(x);
    return *(unsigned short*)&b;
}
__device__ __forceinline__ float bf2f(unsigned short u) {
    unsigned int v = ((unsigned int)u) << 16;
    float f;
    __builtin_memcpy(&f, &v, 4);
    return f;
}
__device__ __forceinline__ short8 pack8(float4 f0, float4 f1) {
    short8 v;
    v[0] = (short)f2bf(f0.x); v[1] = (short)f2bf(f0.y);
    v[2] = (short)f2bf(f0.z); v[3] = (short)f2bf(f0.w);
    v[4] = (short)f2bf(f1.x); v[5] = (short)f2bf(f1.y);
    v[6] = (short)f2bf(f1.z); v[7] = (short)f2bf(f1.w);
    return v;
}

// ---------------- weights f32 -> bf16 ----------------
__global__ void cvt_w_kernel(const float4* __restrict__ wfc, const float4* __restrict__ wres,
                             ushort4* __restrict__ w16, int n4each) {
    int idx = blockIdx.x * blockDim.x + threadIdx.x;
    if (idx >= 2 * n4each) return;
    float4 f = (idx < n4each) ? wfc[idx] : wres[idx - n4each];
    ushort4 u;
    u.x = f2bf(f.x); u.y = f2bf(f.y); u.z = f2bf(f.z); u.w = f2bf(f.w);
    w16[idx] = u;
}

// ---------------- attention-projection columns: ew16[16][256] ----------------
// rows 0-3: al_w[h][k] = sum_d attn_l[h,d]*W_fc[h*32+d][k]; rows 4-7: ar_w; 8-15: 0.
__global__ __launch_bounds__(256) void ew_kernel(const float* __restrict__ wfc,
                                                 const float* __restrict__ attn_l,
                                                 const float* __restrict__ attn_r,
                                                 unsigned short* __restrict__ ew16) {
    int h = blockIdx.x;          // 4 blocks
    int k = threadIdx.x;         // 256
    float sl = 0.f, sr = 0.f;
#pragma unroll 8
    for (int d = 0; d < 32; d++) {
        float w = wfc[(size_t)(h * 32 + d) * IN_F + k];
        sl += attn_l[h * 32 + d] * w;
        sr += attn_r[h * 32 + d] * w;
    }
    ew16[h * IN_F + k] = f2bf(sl);
    ew16[(4 + h) * IN_F + k] = f2bf(sr);
    ew16[(8 + h) * IN_F + k] = 0;
    ew16[(12 + h) * IN_F + k] = 0;
}

// ---------------- per-chunk LDS histogram (uint16-packed, no global atomics) ----
__global__ __launch_bounds__(512) void hist_kernel(const int* __restrict__ src,
                                                   const int* __restrict__ dst,
                                                   unsigned short* __restrict__ pc_src,
                                                   unsigned short* __restrict__ pc_dst,
                                                   int N, int E, int chunk) {
    __shared__ unsigned int h[NMAX / 2];   // 100 KB packed uint16 counts
    int tid = threadIdx.x;
    int nh = N >> 1;                        // N even
    uint4* h4 = (uint4*)h;
    for (int i = tid; i < (nh >> 2); i += 512) h4[i] = make_uint4(0, 0, 0, 0);
    for (int i = (nh & ~3) + tid; i < nh; i += 512) h[i] = 0;
    __syncthreads();

    const int* arr = blockIdx.y ? src : dst;
    int e1 = min(E, (int)(blockIdx.x + 1) * chunk);
    for (int e = blockIdx.x * chunk + tid; e < e1; e += 512) {
        int v = arr[e];
        atomicAdd(&h[v >> 1], 1u << ((v & 1) << 4));
    }
    __syncthreads();

    unsigned short* pc = (blockIdx.y ? pc_src : pc_dst) + (size_t)blockIdx.x * N;
    uint4* pc4 = (uint4*)pc;
    for (int i = tid; i < (nh >> 2); i += 512) pc4[i] = h4[i];
    for (int i = (nh & ~3) + tid; i < nh; i += 512) ((unsigned int*)pc)[i] = h[i];
}

// ---------------- per-node chunk prefix (in place) + degrees + scan1 ----------------
__global__ __launch_bounds__(256) void sum_scan1_kernel(
    const unsigned short* __restrict__ pc_src, unsigned short* __restrict__ pc_dst,
    int* __restrict__ out_cnt, int* __restrict__ deg, int* __restrict__ bsum,
    int N, int C) {
    __shared__ int wsum[4];
    int n = blockIdx.x * 256 + threadIdx.x;
    int sd = 0;
    if (n < N) {
        int ss = 0;
        for (int c = 0; c < C; c++) {
            ss += pc_src[(size_t)c * N + n];
            unsigned short v = pc_dst[(size_t)c * N + n];
            pc_dst[(size_t)c * N + n] = (unsigned short)sd;  // exclusive chunk prefix
            sd += v;
        }
        out_cnt[n] = ss;
        deg[n] = sd;
    }
    int v = (n < N) ? sd : 0;
#pragma unroll
    for (int d = 1; d < 64; d <<= 1) v += __shfl_xor(v, d);
    if ((threadIdx.x & 63) == 0) wsum[threadIdx.x >> 6] = v;
    __syncthreads();
    if (threadIdx.x == 0) bsum[blockIdx.x] = wsum[0] + wsum[1] + wsum[2] + wsum[3];
}

// ---------------- scan of block sums ----------------
__global__ __launch_bounds__(256) void scan2_kernel(int* __restrict__ bsum, int nb,
                                                    int* __restrict__ row_start_N, int E) {
    __shared__ int wtot[4];
    int tid = threadIdx.x, lane = tid & 63, wid = tid >> 6;
    int v = (tid < nb) ? bsum[tid] : 0;
    int incl = v;
#pragma unroll
    for (int d = 1; d < 64; d <<= 1) {
        int t = __shfl_up(incl, d);
        if (lane >= d) incl += t;
    }
    if (lane == 63) wtot[wid] = incl;
    __syncthreads();
    int woff = 0;
    for (int w = 0; w < wid; w++) woff += wtot[w];
    if (tid < nb) bsum[tid] = woff + incl - v;  // exclusive block offset, in place
    if (tid == 0) *row_start_N = E;             // row_start[N]
}

__global__ __launch_bounds__(256) void scan3_kernel(const int* __restrict__ deg,
                                                    const int* __restrict__ boff,
                                                    int* __restrict__ row_start, int N) {
    __shared__ int wsum[4];
    int i = blockIdx.x * 256 + threadIdx.x;
    int lane = threadIdx.x & 63, wid = threadIdx.x >> 6;
    int v = (i < N) ? deg[i] : 0;
    int incl = v;
#pragma unroll
    for (int d = 1; d < 64; d <<= 1) {
        int t = __shfl_up(incl, d);
        if (lane >= d) incl += t;
    }
    if (lane == 63) wsum[wid] = incl;
    __syncthreads();
    int woff = 0;
    for (int w = 0; w < wid; w++) woff += wsum[w];
    int excl = boff[blockIdx.x] + woff + incl - v;
    if (i < N) row_start[i] = excl;
}

// ---------------- placement: LDS cursors seeded from chunk prefix ----------------
__global__ __launch_bounds__(512) void place_kernel(const int* __restrict__ src,
                                                    const int* __restrict__ dst,
                                                    const unsigned short* __restrict__ chunkpre,
                                                    const int* __restrict__ row_start,
                                                    int* __restrict__ esrc,
                                                    int N, int E, int chunk) {
    __shared__ unsigned int cur[NMAX / 2];   // packed uint16 cursors
    int tid = threadIdx.x;
    int nh = N >> 1;
    const unsigned short* cp = chunkpre + (size_t)blockIdx.x * N;
    const uint4* cp4 = (const uint4*)cp;
    uint4* cur4 = (uint4*)cur;
    for (int i = tid; i < (nh >> 2); i += 512) cur4[i] = cp4[i];
    for (int i = (nh & ~3) + tid; i < nh; i += 512) cur[i] = ((const unsigned int*)cp)[i];
    __syncthreads();

    int e1 = min(E, (int)(blockIdx.x + 1) * chunk);
    for (int e = blockIdx.x * chunk + tid; e < e1; e += 512) {
        int d = dst[e], s = src[e];
        int sh = (d & 1) << 4;
        unsigned int old = atomicAdd(&cur[d >> 1], 1u << sh);
        int rank = (old >> sh) & 0xffff;
        esrc[row_start[d] + rank] = s;
    }
}

// ---------------- persistent fused GEMM: B panel in LDS, no spill ----------------
// 256 blocks x 8 waves (512 thr). sB = full 256x256 bf16 weight panel (128 KiB,
// staged once, XOR-swizzled). Per 32-row tile: reg-prefetch f32 A -> cvt -> sA
// (16 KiB) -> pure ds_read+MFMA k-loop. Wave w owns cols w*32..+31; waves 0-3
// write h16 (+norm), 4-7 write resid16; wave 0 also computes el/er via ew16.
__global__ __launch_bounds__(512, 1) void gemm_fused(
    const float* __restrict__ feat, const __hip_bfloat16* __restrict__ w16,
    const __hip_bfloat16* __restrict__ ew16, const int* __restrict__ out_cnt,
    unsigned short* __restrict__ h16, unsigned short* __restrict__ resid16,
    float* __restrict__ el, float* __restrict__ er, int N, int ntiles) {
    __shared__ unsigned short sB[256 * 256];  // 128 KiB
    __shared__ unsigned short sA[32 * 256];   // 16 KiB
    int tid = threadIdx.x;
    int lane = tid & 63, w = tid >> 6;
    int l15 = lane & 15, lg = lane >> 4;
    int c0 = w * 32;
    bool w0 = (w == 0);
    bool isH = (w < 4);
    int colloc = c0 & 127;

    // ---- stage B once: 8192 granules (16 per thread), XOR-swizzled by col ----
#pragma unroll
    for (int it = 0; it < 16; ++it) {
        int idx = it * 512 + tid;
        int c = idx >> 5, g = idx & 31;
        short8 v = *(const short8*)(w16 + (size_t)c * IN_F + g * 8);
        *(short8*)&sB[c * 256 + ((g ^ (c & 7)) * 8)] = v;
    }
    // ew fragment for wave 0 (8 short8 regs)
    short8 ereg[8];
    if (w0) {
        const __hip_bfloat16* ep = ew16 + (size_t)l15 * IN_F + lg * 8;
#pragma unroll
        for (int kk = 0; kk < 8; kk++) ereg[kk] = *(const short8*)(ep + kk * 32);
    }

    // A-stage mapping: granule idx = i*512+tid -> row idx>>5, 8-col group idx&31
    int srow[2], sgc[2];
#pragma unroll
    for (int i = 0; i < 2; i++) {
        int idx = i * 512 + tid;
        srow[i] = idx >> 5;
        sgc[i] = idx & 31;
    }

    float4 fA[2][2];
    int t = blockIdx.x;
    // prologue: load tile t into regs
#pragma unroll
    for (int i = 0; i < 2; i++) {
        int gm = t * 32 + srow[i];
        gm = (gm < N) ? gm : (N - 1);
        const float4* fp = (const float4*)(feat + (size_t)gm * IN_F + sgc[i] * 8);
        fA[i][0] = fp[0];
        fA[i][1] = fp[1];
    }

    for (; t < ntiles; t += GGRID) {
        __syncthreads();   // all waves done reading sA (and, first iter, sB staged)
        // ---- convert prefetched regs -> sA (fA holds tile t) ----
#pragma unroll
        for (int i = 0; i < 2; i++)
            *(short8*)&sA[srow[i] * 256 + ((sgc[i] ^ (srow[i] & 7)) * 8)] =
                pack8(fA[i][0], fA[i][1]);
        __syncthreads();   // sA staged

        // ---- issue next tile's loads (latency hides under k-loop + epilogue) ----
        int tn = t + GGRID;
        if (tn < ntiles) {
#pragma unroll
            for (int i = 0; i < 2; i++) {
                int gm = tn * 32 + srow[i];
                gm = (gm < N) ? gm : (N - 1);
                const float4* fp = (const float4*)(feat + (size_t)gm * IN_F + sgc[i] * 8);
                fA[i][0] = fp[0];
                fA[i][1] = fp[1];
            }
        }

        // ---- k-loop: pure LDS reads + MFMA ----
        f32x4 acc[2][2], accE[2];
#pragma unroll
        for (int i = 0; i < 2; i++) {
            accE[i] = (f32x4){0.f, 0.f, 0.f, 0.f};
#pragma unroll
            for (int j = 0; j < 2; j++) acc[i][j] = (f32x4){0.f, 0.f, 0.f, 0.f};
        }
#pragma unroll
        for (int kk = 0; kk < 8; kk++) {
            short8 a[2], b[2];
#pragma unroll
            for (int mi = 0; mi < 2; mi++) {
                int row = mi * 16 + l15;
                int gs = (kk * 4 + lg) ^ (row & 7);
                a[mi] = *(const short8*)&sA[row * 256 + gs * 8];
            }
#pragma unroll
            for (int ni = 0; ni < 2; ni++) {
                int c = c0 + ni * 16 + l15;
                int gsb = (kk * 4 + lg) ^ (c & 7);
                b[ni] = *(const short8*)&sB[c * 256 + gsb * 8];
            }
#pragma unroll
            for (int mi = 0; mi < 2; mi++)
#pragma unroll
                for (int ni = 0; ni < 2; ni++)
                    acc[mi][ni] = __builtin_amdgcn_mfma_f32_16x16x32_bf16(
                        a[mi], b[ni], acc[mi][ni], 0, 0, 0);
            if (w0) {
#pragma unroll
                for (int mi = 0; mi < 2; mi++)
                    accE[mi] = __builtin_amdgcn_mfma_f32_16x16x32_bf16(
                        a[mi], ereg[kk], accE[mi], 0, 0, 0);
            }
        }

        // ---- epilogue. C/D: col = lane&15, row = 4*(lane>>4)+reg ----
        int bm = t * 32;
#pragma unroll
        for (int mi = 0; mi < 2; mi++) {
#pragma unroll
            for (int reg = 0; reg < 4; reg++) {
                int r = bm + mi * 16 + lg * 4 + reg;
                bool valid = (r < N);
                int rr = valid ? r : 0;
                if (isH) {
                    float nrm = rsqrtf(fmaxf((float)out_cnt[rr], 1.0f));
                    if (valid) {
#pragma unroll
                        for (int ni = 0; ni < 2; ni++)
                            h16[(size_t)r * HD + colloc + ni * 16 + l15] =
                                f2bf(acc[mi][ni][reg] * nrm);
                        if (w0) {
                            float ev = accE[mi][reg];  // l15<4: el, 4..7: er
                            if (l15 < 4) el[r * 4 + l15] = ev * nrm;
                            else if (l15 < 8) er[r * 4 + (l15 - 4)] = ev;
                        }
                    }
                } else if (valid) {
#pragma unroll
                    for (int ni = 0; ni < 2; ni++)
                        resid16[(size_t)r * HD + colloc + ni * 16 + l15] =
                            f2bf(acc[mi][ni][reg]);
                }
            }
        }
    }
}

// ---------------- fused edge softmax + weighted scatter + final ----------------
// One wave per dst node, lane-transposed: 64 lanes = 4 edge-slots x 16 dim-lanes.
// 2-stage software pipeline; final write = sc*acc + resid16 (out written once).
__global__ __launch_bounds__(256) void agg_kernel(const unsigned short* __restrict__ h16,
                                                  const float* __restrict__ el,
                                                  const float* __restrict__ er,
                                                  const int* __restrict__ row_start,
                                                  const int* __restrict__ esrc,
                                                  const unsigned short* __restrict__ resid16,
                                                  float* __restrict__ out, int N) {
    int wid = threadIdx.x >> 6, lane = threadIdx.x & 63;
    int n = blockIdx.x * 4 + wid;
    if (n >= N) return;
    int es = lane >> 4;        // edge slot 0..3
    int l15 = lane & 15;
    int h = l15 >> 2;          // head owning this lane's 8 dims
    int d0 = l15 * 8;
    int beg = row_start[n], end = row_start[n + 1];
    float erh = er[n * 4 + h];
    float den = 0.f;
    float acc[8];
#pragma unroll
    for (int j = 0; j < 8; j++) acc[j] = 0.f;

    if (beg < end) {
        bool ok0, ok1;
        float ev0, ev1; short8 hv0, hv1;
        {
            int i0 = beg + es, i1 = beg + 4 + es;
            ok0 = i0 < end; ok1 = i1 < end;
            int s0 = esrc[ok0 ? i0 : beg];
            int s1 = esrc[ok1 ? i1 : beg];
            ev0 = el[s0 * 4 + h]; ev1 = el[s1 * 4 + h];
            hv0 = *(const short8*)(h16 + (size_t)s0 * HD + d0);
            hv1 = *(const short8*)(h16 + (size_t)s1 * HD + d0);
        }
        for (int base = beg + 8; base < end; base += 8) {
            int i0 = base + es, i1 = base + 4 + es;
            bool p0 = i0 < end, p1 = i1 < end;
            int t0 = esrc[p0 ? i0 : beg];
            int t1 = esrc[p1 ? i1 : beg];
            float fv0 = el[t0 * 4 + h];
            float fv1 = el[t1 * 4 + h];
            short8 g0 = *(const short8*)(h16 + (size_t)t0 * HD + d0);
            short8 g1 = *(const short8*)(h16 + (size_t)t1 * HD + d0);
            float e0 = ev0 + erh; e0 = (e0 > 0.f) ? e0 : NEG_SLOPE * e0;
            float e1 = ev1 + erh; e1 = (e1 > 0.f) ? e1 : NEG_SLOPE * e1;
            float ex0 = ok0 ? __expf(e0) : 0.f;
            float ex1 = ok1 ? __expf(e1) : 0.f;
            den += ex0 + ex1;
#pragma unroll
            for (int j = 0; j < 8; j++)
                acc[j] += ex0 * bf2f((unsigned short)hv0[j]) +
                          ex1 * bf2f((unsigned short)hv1[j]);
            ok0 = p0; ok1 = p1; ev0 = fv0; ev1 = fv1; hv0 = g0; hv1 = g1;
        }
        float e0 = ev0 + erh; e0 = (e0 > 0.f) ? e0 : NEG_SLOPE * e0;
        float e1 = ev1 + erh; e1 = (e1 > 0.f) ? e1 : NEG_SLOPE * e1;
        float ex0 = ok0 ? __expf(e0) : 0.f;
        float ex1 = ok1 ? __expf(e1) : 0.f;
        den += ex0 + ex1;
#pragma unroll
        for (int j = 0; j < 8; j++)
            acc[j] += ex0 * bf2f((unsigned short)hv0[j]) +
                      ex1 * bf2f((unsigned short)hv1[j]);
    }

#pragma unroll
    for (int m = 16; m < 64; m <<= 1) {
        den += __shfl_xor(den, m);
#pragma unroll
        for (int j = 0; j < 8; j++) acc[j] += __shfl_xor(acc[j], m);
    }

    if (es == 0) {
        const unsigned short* rp = resid16 + (size_t)n * HD + d0;
        short8 rv = *(const short8*)rp;
        int indeg = end - beg;
        float sc = (indeg > 0) ? sqrtf((float)indeg) / den : 0.f;
        float o[8];
#pragma unroll
        for (int j = 0; j < 8; j++)
            o[j] = sc * acc[j] + bf2f((unsigned short)rv[j]);
        float* op = out + (size_t)n * HD + d0;
        *(float4*)op = make_float4(o[0], o[1], o[2], o[3]);
        *(float4*)(op + 4) = make_float4(o[4], o[5], o[6], o[7]);
    }
}

extern "C" void kernel_launch(void* const* d_in, const int* in_sizes, int n_in,
                              void* d_out, int out_size, void* d_ws, size_t ws_size,
                              hipStream_t stream) {
    const float* feat   = (const float*)d_in[0];
    const int*   src    = (const int*)d_in[1];
    const int*   dst    = (const int*)d_in[2];
    const float* W_fc   = (const float*)d_in[3];
    const float* attn_l = (const float*)d_in[4];
    const float* attn_r = (const float*)d_in[5];
    const float* W_res  = (const float*)d_in[6];
    float* out = (float*)d_out;

    int N = in_sizes[0] / IN_F;   // 50000
    int E = in_sizes[1];          // 800000
    int nb = (N + 255) / 256;     // 196 (<= 256 for scan2)

    size_t off = 0;
    auto alloc = [&](size_t bytes) {
        size_t o = off;
        off = (off + bytes + 255) & ~(size_t)255;
        return o;
    };
    char* ws = (char*)d_ws;
    unsigned short* h16     = (unsigned short*)(ws + alloc((size_t)N * HD * 2));
    unsigned short* resid16 = (unsigned short*)(ws + alloc((size_t)N * HD * 2));
    __hip_bfloat16* w16     = (__hip_bfloat16*)(ws + alloc((size_t)2 * HD * IN_F * 2));
    unsigned short* ew16    = (unsigned short*)(ws + alloc((size_t)16 * IN_F * 2));
    float* el               = (float*)(ws + alloc((size_t)N * 4 * 4));
    float* er               = (float*)(ws + alloc((size_t)N * 4 * 4));
    int* out_cnt            = (int*)(ws + alloc((size_t)N * 4));
    int* deg                = (int*)(ws + alloc((size_t)N * 4));
    int* row_start          = (int*)(ws + alloc((size_t)(N + 1) * 4));
    int* bsum               = (int*)(ws + alloc((size_t)nb * 4));
    int* esrc               = (int*)(ws + alloc((size_t)E * 4));

    // runtime-adaptive chunk count: each chunk needs 2 uint16 rows of N
    size_t per_chunk = (size_t)4 * N;
    size_t avail = (ws_size > off + 4096) ? (ws_size - off - 4096) : 0;
    int C = (int)(avail / per_chunk);
    if (C > 128) C = 128;
    if (C < 32) C = 32;           // round-6 footprint proved safe
    unsigned short* pc_dst = (unsigned short*)(ws + alloc((size_t)C * N * 2));
    unsigned short* pc_src = (unsigned short*)(ws + alloc((size_t)C * N * 2));
    int chunk = (E + C - 1) / C;

    int n4each = HD * IN_F / 4;
    cvt_w_kernel<<<(2 * n4each + 255) / 256, 256, 0, stream>>>(
        (const float4*)W_fc, (const float4*)W_res, (ushort4*)w16, n4each);
    ew_kernel<<<4, 256, 0, stream>>>(W_fc, attn_l, attn_r, ew16);

    hist_kernel<<<dim3(C, 2), 512, 0, stream>>>(src, dst, pc_src, pc_dst, N, E, chunk);
    sum_scan1_kernel<<<nb, 256, 0, stream>>>(pc_src, pc_dst, out_cnt, deg, bsum, N, C);
    scan2_kernel<<<1, 256, 0, stream>>>(bsum, nb, row_start + N, E);
    scan3_kernel<<<nb, 256, 0, stream>>>(deg, bsum, row_start, N);
    place_kernel<<<C, 512, 0, stream>>>(src, dst, pc_dst, row_start, esrc, N, E, chunk);

    int ntiles = (N + 31) / 32;
    gemm_fused<<<GGRID, 512, 0, stream>>>(feat, (const __hip_bfloat16*)w16,
                                          (const __hip_bfloat16*)ew16, out_cnt,
                                          h16, resid16, el, er, N, ntiles);

    int nb4 = (N + 3) / 4;
    agg_kernel<<<nb4, 256, 0, stream>>>(h16, el, er, row_start, esrc, resid16, out, N);
}